// Round 2
// baseline (1870.843 us; speedup 1.0000x reference)
//
#include <hip/hip_runtime.h>
#include <hip/hip_bf16.h>

// Problem constants
#define BB   2
#define SS   1024
#define DD   1024
#define HH   8
#define NPP  2
#define NKK  32
#define DKK  64
#define TKK  8
#define NKV_ 1024

#define TILE 64
#define KT   16
#define LPAD 4   // LDS pad: float4-aligned stride 68; 2-way bank alias is free

typedef __hip_bfloat16 bf16;

// ---- typed 4-wide load/store helpers (bf16 <-> fp32) ----
__device__ inline float4 ld4(const float* p) { return *(const float4*)p; }
__device__ inline float4 ld4(const bf16* p) {
    ushort4 u = *(const ushort4*)p;
    float4 f;
    f.x = __uint_as_float(((unsigned)u.x) << 16);
    f.y = __uint_as_float(((unsigned)u.y) << 16);
    f.z = __uint_as_float(((unsigned)u.z) << 16);
    f.w = __uint_as_float(((unsigned)u.w) << 16);
    return f;
}
__device__ inline unsigned short f2b(float f) {       // RNE f32->bf16
    unsigned x = __float_as_uint(f);
    return (unsigned short)((x + 0x7fffu + ((x >> 16) & 1u)) >> 16);
}
__device__ inline float b2f(unsigned short u) {
    return __uint_as_float(((unsigned)u) << 16);
}
__device__ inline void st4(float* p, float4 v) { *(float4*)p = v; }
__device__ inline void st4(bf16* p, float4 v) {
    ushort4 u; u.x = f2b(v.x); u.y = f2b(v.y); u.z = f2b(v.z); u.w = f2b(v.w);
    *(ushort4*)p = u;
}

// Generic tiled GEMM, fp32 accumulate, typed operands:
//   C[m,n] = scale * sum_k A[m*lda+k] * (TRANSB ? B[n*ldb+k] : B[k*ldb+n])
// grid.z slabs: z -> (zb=z/zH, zh=z%zH) with per-operand strides.
// CAUSAL==1: skip tiles fully above diagonal. CAUSAL==2: K limited to row0+TILE.
template<typename TA, typename TB, typename TC, int TRANSB, int CAUSAL>
__global__ __launch_bounds__(256) void gemm_t(
    const TA* __restrict__ A, const TB* __restrict__ Bm, TC* __restrict__ C,
    int K, int lda, int ldb, int ldc,
    long long sAb, long long sAh, long long sBb, long long sBh,
    long long sCb, long long sCh, int zH, float scale)
{
    int z  = blockIdx.z;
    int zb = z / zH, zh = z % zH;
    A  += (long long)zb * sAb + (long long)zh * sAh;
    Bm += (long long)zb * sBb + (long long)zh * sBh;
    C  += (long long)zb * sCb + (long long)zh * sCh;

    int row0 = blockIdx.y * TILE;
    int col0 = blockIdx.x * TILE;
    if (CAUSAL == 1 && col0 > row0 + (TILE - 1)) return;
    int Klim = (CAUSAL == 2) ? min(K, row0 + TILE) : K;

    __shared__ float As[KT][TILE + LPAD];
    __shared__ float Bs[KT][TILE + LPAD];

    int tid = threadIdx.x;
    int tx = tid % 16, ty = tid / 16;
    float acc[4][4] = {{0.f}};

    int lr = tid / 4;          // 0..63
    int lk = (tid % 4) * 4;    // 0,4,8,12

    for (int k0 = 0; k0 < Klim; k0 += KT) {
        {
            float4 v = ld4(&A[(long long)(row0 + lr) * lda + k0 + lk]);
            As[lk + 0][lr] = v.x; As[lk + 1][lr] = v.y;
            As[lk + 2][lr] = v.z; As[lk + 3][lr] = v.w;
        }
        if (TRANSB) {
            float4 v = ld4(&Bm[(long long)(col0 + lr) * ldb + k0 + lk]);
            Bs[lk + 0][lr] = v.x; Bs[lk + 1][lr] = v.y;
            Bs[lk + 2][lr] = v.z; Bs[lk + 3][lr] = v.w;
        } else {
            int kk = tid / 16, nn = (tid % 16) * 4;
            float4 v = ld4(&Bm[(long long)(k0 + kk) * ldb + col0 + nn]);
            Bs[kk][nn + 0] = v.x; Bs[kk][nn + 1] = v.y;
            Bs[kk][nn + 2] = v.z; Bs[kk][nn + 3] = v.w;
        }
        __syncthreads();
        #pragma unroll
        for (int kk = 0; kk < KT; ++kk) {
            float a[4], b[4];
            #pragma unroll
            for (int i = 0; i < 4; ++i) a[i] = As[kk][ty * 4 + i];
            #pragma unroll
            for (int j = 0; j < 4; ++j) b[j] = Bs[kk][tx * 4 + j];
            #pragma unroll
            for (int i = 0; i < 4; ++i)
                #pragma unroll
                for (int j = 0; j < 4; ++j)
                    acc[i][j] = fmaf(a[i], b[j], acc[i][j]);
        }
        __syncthreads();
    }

    #pragma unroll
    for (int i = 0; i < 4; ++i) {
        float4 o = make_float4(scale * acc[i][0], scale * acc[i][1],
                               scale * acc[i][2], scale * acc[i][3]);
        st4(&C[(long long)(row0 + ty * 4 + i) * ldc + col0 + tx * 4], o);
    }
}

// Product-key routing: one 64-thread block per (b,s,h). jax.lax.top_k
// semantics: descending, ties -> lowest index. All fp32.
__global__ __launch_bounds__(64) void pk_route(
    const float* __restrict__ pq, const float* __restrict__ pkk,
    float* __restrict__ wts, int* __restrict__ idxs)
{
    int bid = blockIdx.x;                 // (b*S+s)*H + h
    int h   = bid % HH;
    long long bs = bid / HH;
    int t = threadIdx.x;
    int p = t >> 5, n = t & 31;

    const float* pv = pq  + (bs * NPP + p) * (HH * DKK) + h * DKK;
    const float* kv = pkk + ((long long)(p * NKK + n) * HH + h) * DKK;
    float s = 0.f;
    #pragma unroll 8
    for (int d = 0; d < DKK; ++d) s = fmaf(pv[d], kv[d], s);

    __shared__ float sim[64];
    __shared__ float psc[2][TKK];
    __shared__ int   pix[2][TKK];
    sim[t] = s;
    __syncthreads();

    if ((t & 31) == 0) {
        int pp = t >> 5;
        unsigned used = 0;
        for (int r = 0; r < TKK; ++r) {
            float best = -3.4e38f; int bi = 0;
            for (int m = 0; m < NKK; ++m) {
                float v = sim[pp * NKK + m];
                if (!((used >> m) & 1u) && v > best) { best = v; bi = m; }
            }
            used |= (1u << bi);
            psc[pp][r] = best; pix[pp][r] = bi;
        }
    }
    __syncthreads();

    if (t == 0) {
        float cs[64]; int ci[64];
        #pragma unroll
        for (int i = 0; i < TKK; ++i)
            #pragma unroll
            for (int j = 0; j < TKK; ++j) {
                cs[i * TKK + j] = psc[0][i] + psc[1][j];
                ci[i * TKK + j] = pix[0][i] + pix[1][j] * NKK;
            }
        unsigned long long used = 0ull;
        float fs[TKK]; int fi[TKK];
        for (int r = 0; r < TKK; ++r) {
            float best = -3.4e38f; int bf = 0;
            for (int f = 0; f < 64; ++f)
                if (!((used >> f) & 1ull) && cs[f] > best) { best = cs[f]; bf = f; }
            used |= (1ull << bf);
            fs[r] = best; fi[r] = ci[bf];
        }
        float mx = fs[0];
        float e[TKK], sum = 0.f;
        for (int r = 0; r < TKK; ++r) { e[r] = expf(fs[r] - mx); sum += e[r]; }
        float inv = 1.f / sum;
        for (int r = 0; r < TKK; ++r) {
            wts[(long long)bid * TKK + r]  = e[r] * inv;
            idxs[(long long)bid * TKK + r] = fi[r] + h * NKV_;
        }
    }
}

// Weighted 8-row embedding-bag gather -> k,v in [B,H,S,D], bf16 out.
__global__ __launch_bounds__(256) void gather_kv(
    const float* __restrict__ ke, const float* __restrict__ ve,
    const float* __restrict__ wts, const int* __restrict__ idxs,
    bf16* __restrict__ kb, bf16* __restrict__ vb)
{
    int bid = blockIdx.x;                 // (b*S+s)*H + h
    int h = bid % HH;
    int bs = bid / HH;
    int b = bs / SS, s = bs % SS;

    float w[TKK]; int rix[TKK];
    #pragma unroll
    for (int t = 0; t < TKK; ++t) {
        w[t]   = wts[(long long)bid * TKK + t];
        rix[t] = idxs[(long long)bid * TKK + t];
    }
    int c0 = threadIdx.x * 4;
    float4 ak = {0.f,0.f,0.f,0.f}, av = {0.f,0.f,0.f,0.f};
    #pragma unroll
    for (int t = 0; t < TKK; ++t) {
        float4 kr = *(const float4*)&ke[(long long)rix[t] * DD + c0];
        float4 vr = *(const float4*)&ve[(long long)rix[t] * DD + c0];
        ak.x += w[t]*kr.x; ak.y += w[t]*kr.y; ak.z += w[t]*kr.z; ak.w += w[t]*kr.w;
        av.x += w[t]*vr.x; av.y += w[t]*vr.y; av.z += w[t]*vr.z; av.w += w[t]*vr.w;
    }
    long long off = ((long long)(b * HH + h) * SS + s) * DD + c0;
    st4(&kb[off], ak);
    st4(&vb[off], av);
}

// Causal softmax on bf16 score rows; fp32 compute, single rounded store.
// Each thread owns 4 columns (S=1024, 256 threads).
__global__ __launch_bounds__(256) void softmax_causal_bf(bf16* __restrict__ sc)
{
    int r  = blockIdx.x;                  // (b*H+h)*S + sq
    int sq = r % SS;
    unsigned short* row = (unsigned short*)(sc + (long long)r * SS);
    int t = threadIdx.x;
    int nvalid = sq + 1;

    float v[4];
    float lm = -INFINITY;
    #pragma unroll
    for (int i = 0; i < 4; ++i) {
        int j = t + i * 256;
        v[i] = (j < nvalid) ? b2f(row[j]) : -INFINITY;
        lm = fmaxf(lm, v[i]);
    }
    __shared__ float red[256];
    red[t] = lm; __syncthreads();
    for (int o = 128; o > 0; o >>= 1) {
        if (t < o) red[t] = fmaxf(red[t], red[t + o]);
        __syncthreads();
    }
    float m = red[0];
    __syncthreads();

    float e[4], ls = 0.f;
    #pragma unroll
    for (int i = 0; i < 4; ++i) {
        int j = t + i * 256;
        e[i] = (j < nvalid) ? expf(v[i] - m) : 0.f;
        ls += e[i];
    }
    red[t] = ls; __syncthreads();
    for (int o = 128; o > 0; o >>= 1) {
        if (t < o) red[t] += red[t + o];
        __syncthreads();
    }
    float inv = 1.f / red[0];
    #pragma unroll
    for (int i = 0; i < 4; ++i) row[t + i * 256] = f2b(e[i] * inv);
}

extern "C" void kernel_launch(void* const* d_in, const int* in_sizes, int n_in,
                              void* d_out, int out_size, void* d_ws, size_t ws_size,
                              hipStream_t stream)
{
    const float* inputs     = (const float*)d_in[0];
    const float* Wq         = (const float*)d_in[1];
    const float* Wpk        = (const float*)d_in[2];
    const float* pk_keys    = (const float*)d_in[3];
    const float* keys_emb   = (const float*)d_in[4];
    const float* values_emb = (const float*)d_in[5];
    const float* Wo         = (const float*)d_in[6];
    float* out = (float*)d_out;

    // ---- workspace layout (total ~129 MB) ----
    const long long NBHSD = (long long)BB * HH * SS * DD;    // 16,777,216
    const long long SLAB  = (long long)SS * HH * DD;         // per-batch q/ctx slab
    bf16* kb  = (bf16*)d_ws;                 // [B,H,S,D]  32MB
    bf16* vb  = kb + NBHSD;                  // [B,H,S,D]  32MB
    bf16* qc  = vb + NBHSD;                  // q then ctx, [B,S,H*D]  32MB
    bf16* scb = qc + NBHSD;                  // [B*H,S,S]  32MB
    float* pqb = (float*)scb;                // aliases scb (dead before scores)
    float* wtb = (float*)(scb + NBHSD);      // [B,S,H,8] fp32  512KB
    int*   ixb = (int*)(wtb + (long long)BB * SS * HH * TKK);  // 512KB
    size_t needed = (size_t)(((char*)(ixb + (long long)BB * SS * HH * TKK)) - (char*)d_ws);
    if (ws_size < needed) return;   // diagnostic: output stays zero

    // 1. pq = inputs @ Wpk^T  (fp32, routing precision)
    gemm_t<float, float, float, 1, 0><<<dim3(16, 32, 1), 256, 0, stream>>>(
        inputs, Wpk, pqb, 1024, 1024, 1024, 1024,
        0, 0, 0, 0, 0, 0, 1, 1.0f);

    // 2. product-key routing -> fp32 weights + row indices
    pk_route<<<dim3(BB * SS * HH), 64, 0, stream>>>(pqb, pk_keys, wtb, ixb);

    // 3. weighted embedding gather -> k,v [B,H,S,D] bf16
    gather_kv<<<dim3(BB * SS * HH), 256, 0, stream>>>(
        keys_emb, values_emb, wtb, ixb, kb, vb);

    // 4. q = (inputs @ Wq^T) * d^-0.5 -> [B,S,H*D] bf16
    gemm_t<float, float, bf16, 1, 0><<<dim3(128, 32, 1), 256, 0, stream>>>(
        inputs, Wq, qc, 1024, 1024, 1024, 8192,
        0, 0, 0, 0, 0, 0, 1, 0.03125f);

    // 5. scores = q @ k^T per (b,h), causal tile-skip -> bf16 [16][S,S]
    gemm_t<bf16, bf16, bf16, 1, 1><<<dim3(16, 16, BB * HH), 256, 0, stream>>>(
        qc, kb, scb, 1024, 8192, 1024, 1024,
        SLAB, (long long)DD, (long long)HH * SS * DD, (long long)SS * DD,
        (long long)HH * SS * SS, (long long)SS * SS, HH, 1.0f);

    // 6. causal softmax (fp32 compute, bf16 store; zeros masked tail)
    softmax_causal_bf<<<dim3(BB * HH * SS), 256, 0, stream>>>(scb);

    // 7. ctx = att @ v per (b,h), K limited to row0+64; ctx overwrites q slab
    gemm_t<bf16, bf16, bf16, 0, 2><<<dim3(16, 16, BB * HH), 256, 0, stream>>>(
        scb, vb, qc, 1024, 1024, 1024, 8192,
        (long long)HH * SS * SS, (long long)SS * SS,
        (long long)HH * SS * DD, (long long)SS * DD,
        SLAB, (long long)DD, HH, 1.0f);

    // 8. out = ctx @ Wo^T  (fp32 out)
    gemm_t<bf16, float, float, 1, 0><<<dim3(16, 32, 1), 256, 0, stream>>>(
        qc, Wo, out, 8192, 8192, 8192, 1024,
        0, 0, 0, 0, 0, 0, 1, 1.0f);
}

// Round 3
// 672.748 us; speedup vs baseline: 2.7809x; 2.7809x over previous
//
#include <hip/hip_runtime.h>
#include <hip/hip_bf16.h>

// Problem constants
#define BB   2
#define SS   1024
#define DD   1024
#define HH   8
#define NPP  2
#define NKK  32
#define DKK  64
#define TKK  8
#define NKV_ 1024

typedef __hip_bfloat16 bf16;
typedef __attribute__((ext_vector_type(8))) short bf16x8;
typedef __attribute__((ext_vector_type(4))) float f32x4;

using u32g = __attribute__((address_space(1))) unsigned int;
using u32l = __attribute__((address_space(3))) unsigned int;

// async global->LDS, 16B per lane; LDS dest = wave-uniform base + lane*16
#define GLDS16(g, l) __builtin_amdgcn_global_load_lds((const u32g*)(g), (u32l*)(l), 16, 0, 0)

// ---- scalar/vec conversion helpers ----
__device__ inline unsigned short f2b(float f) {       // RNE f32->bf16
    unsigned x = __float_as_uint(f);
    return (unsigned short)((x + 0x7fffu + ((x >> 16) & 1u)) >> 16);
}
__device__ inline float b2f(unsigned short u) {
    return __uint_as_float(((unsigned)u) << 16);
}
__device__ inline void cstore(bf16* p, float v)  { *(unsigned short*)p = f2b(v); }
__device__ inline void cstore(float* p, float v) { *p = v; }

// fp32 -> bf16 convert, 4 elems/thread
__global__ __launch_bounds__(256) void cvt_bf(const float* __restrict__ src,
                                              bf16* __restrict__ dst, long long n)
{
    long long i = ((long long)blockIdx.x * 256 + threadIdx.x) * 4;
    if (i >= n) return;
    float4 v = *(const float4*)&src[i];
    ushort4 u; u.x = f2b(v.x); u.y = f2b(v.y); u.z = f2b(v.z); u.w = f2b(v.w);
    *(ushort4*)&dst[i] = u;
}

// ============================================================================
// MFMA bf16 GEMM (m97 structure): C[m,n] = scale * sum_k A[m][k] * B[n][k]
// 128x128 tile, BK=64, 4 waves (2x2 of 64x64), mfma_f32_16x16x32_bf16.
// CAUSAL==1: skip tiles fully above diagonal. CAUSAL==2: Klim = row0+128.
// ============================================================================
template<typename TC, int CAUSAL>
__global__ __launch_bounds__(256) void mgemm(
    const bf16* __restrict__ A, const bf16* __restrict__ B, TC* __restrict__ C,
    int K, int lda, int ldb, int ldc,
    long long sAb, long long sAh, long long sBb, long long sBh,
    long long sCb, long long sCh, int zH, float scale)
{
    int z = blockIdx.z, zb = z / zH, zh = z % zH;
    A += (long long)zb * sAb + (long long)zh * sAh;
    B += (long long)zb * sBb + (long long)zh * sBh;
    C += (long long)zb * sCb + (long long)zh * sCh;

    int row0 = blockIdx.y * 128, col0 = blockIdx.x * 128;
    if (CAUSAL == 1 && col0 > row0 + 127) return;
    int Klim = (CAUSAL == 2) ? min(K, row0 + 128) : K;

    __shared__ short As[128 * 64];
    __shared__ short Bs[128 * 64];

    int tid = threadIdx.x, wave = tid >> 6, lane = tid & 63;
    int wr = wave >> 1, wc = wave & 1;       // wave's 64x64 quadrant
    int lr = lane & 15, lg = lane >> 4;      // frag row / k-group

    f32x4 zero = {0.f, 0.f, 0.f, 0.f};
    f32x4 acc[4][4];
    #pragma unroll
    for (int m = 0; m < 4; ++m)
        #pragma unroll
        for (int n = 0; n < 4; ++n) acc[m][n] = zero;

    // staging geometry: each wave stages 32 rows of A and of B per K-step;
    // one GLDS16 covers 8 rows (64 lanes x 16B = 8 rows x 128B).
    int srow = wave * 32 + (lane >> 3);      // global row this lane fetches
    int scol = (lane & 7) * 8;               // element col within 64-wide k-tile

    for (int k0 = 0; k0 < Klim; k0 += 64) {
        const bf16* Ak = A + (long long)(row0 + srow) * lda + k0 + scol;
        const bf16* Bk = B + (long long)(col0 + srow) * ldb + k0 + scol;
        #pragma unroll
        for (int i = 0; i < 4; ++i) {
            GLDS16(Ak + (long long)i * 8 * lda, &As[(wave * 32 + i * 8) * 64]);
            GLDS16(Bk + (long long)i * 8 * ldb, &Bs[(wave * 32 + i * 8) * 64]);
        }
        asm volatile("s_waitcnt vmcnt(0)" ::: "memory");
        __syncthreads();

        #pragma unroll
        for (int kk = 0; kk < 2; ++kk) {
            bf16x8 af[4], bfr[4];
            #pragma unroll
            for (int m = 0; m < 4; ++m)
                af[m] = *(const bf16x8*)&As[(wr * 64 + m * 16 + lr) * 64 + kk * 32 + lg * 8];
            #pragma unroll
            for (int n = 0; n < 4; ++n)
                bfr[n] = *(const bf16x8*)&Bs[(wc * 64 + n * 16 + lr) * 64 + kk * 32 + lg * 8];
            #pragma unroll
            for (int m = 0; m < 4; ++m)
                #pragma unroll
                for (int n = 0; n < 4; ++n)
                    acc[m][n] = __builtin_amdgcn_mfma_f32_16x16x32_bf16(
                        af[m], bfr[n], acc[m][n], 0, 0, 0);
        }
        __syncthreads();
    }

    // C/D layout: col = lane&15, row = (lane>>4)*4 + r  [m89-verified]
    #pragma unroll
    for (int m = 0; m < 4; ++m) {
        int row = row0 + wr * 64 + m * 16 + lg * 4;
        #pragma unroll
        for (int n = 0; n < 4; ++n) {
            int col = col0 + wc * 64 + n * 16 + lr;
            #pragma unroll
            for (int r = 0; r < 4; ++r)
                cstore(&C[(long long)(row + r) * ldc + col], scale * acc[m][n][r]);
        }
    }
}

// ============================================================================
// fp32 vector GEMM (kept for the routing projection only):
//   C[m,n] = sum_k A[m*1024+k] * B[n*1024+k]   (M=2048, N=1024, K=1024)
// ============================================================================
#define TILE 64
#define KT   16
#define LPAD 4
__global__ __launch_bounds__(256) void gemm_f32t(
    const float* __restrict__ A, const float* __restrict__ Bm, float* __restrict__ C)
{
    int row0 = blockIdx.y * TILE, col0 = blockIdx.x * TILE;
    __shared__ float As[KT][TILE + LPAD];
    __shared__ float Bs[KT][TILE + LPAD];
    int tid = threadIdx.x, tx = tid % 16, ty = tid / 16;
    float acc[4][4] = {{0.f}};
    int lr = tid / 4, lk = (tid % 4) * 4;

    for (int k0 = 0; k0 < 1024; k0 += KT) {
        float4 va = *(const float4*)&A[(long long)(row0 + lr) * 1024 + k0 + lk];
        As[lk + 0][lr] = va.x; As[lk + 1][lr] = va.y;
        As[lk + 2][lr] = va.z; As[lk + 3][lr] = va.w;
        float4 vb = *(const float4*)&Bm[(long long)(col0 + lr) * 1024 + k0 + lk];
        Bs[lk + 0][lr] = vb.x; Bs[lk + 1][lr] = vb.y;
        Bs[lk + 2][lr] = vb.z; Bs[lk + 3][lr] = vb.w;
        __syncthreads();
        #pragma unroll
        for (int kk = 0; kk < KT; ++kk) {
            float a[4], b[4];
            #pragma unroll
            for (int i = 0; i < 4; ++i) a[i] = As[kk][ty * 4 + i];
            #pragma unroll
            for (int j = 0; j < 4; ++j) b[j] = Bs[kk][tx * 4 + j];
            #pragma unroll
            for (int i = 0; i < 4; ++i)
                #pragma unroll
                for (int j = 0; j < 4; ++j)
                    acc[i][j] = fmaf(a[i], b[j], acc[i][j]);
        }
        __syncthreads();
    }
    #pragma unroll
    for (int i = 0; i < 4; ++i)
        *(float4*)&C[(long long)(row0 + ty * 4 + i) * 1024 + col0 + tx * 4] =
            make_float4(acc[i][0], acc[i][1], acc[i][2], acc[i][3]);
}

// Product-key routing: one 64-thread block per (b,s,h). jax.lax.top_k
// semantics: descending, ties -> lowest index. All fp32.
__global__ __launch_bounds__(64) void pk_route(
    const float* __restrict__ pq, const float* __restrict__ pkk,
    float* __restrict__ wts, int* __restrict__ idxs)
{
    int bid = blockIdx.x;                 // (b*S+s)*H + h
    int h   = bid % HH;
    long long bs = bid / HH;
    int t = threadIdx.x;
    int p = t >> 5, n = t & 31;

    const float* pv = pq  + (bs * NPP + p) * (HH * DKK) + h * DKK;
    const float* kv = pkk + ((long long)(p * NKK + n) * HH + h) * DKK;
    float s = 0.f;
    #pragma unroll 8
    for (int d = 0; d < DKK; ++d) s = fmaf(pv[d], kv[d], s);

    __shared__ float sim[64];
    __shared__ float psc[2][TKK];
    __shared__ int   pix[2][TKK];
    sim[t] = s;
    __syncthreads();

    if ((t & 31) == 0) {
        int pp = t >> 5;
        unsigned used = 0;
        for (int r = 0; r < TKK; ++r) {
            float best = -3.4e38f; int bi = 0;
            for (int m = 0; m < NKK; ++m) {
                float v = sim[pp * NKK + m];
                if (!((used >> m) & 1u) && v > best) { best = v; bi = m; }
            }
            used |= (1u << bi);
            psc[pp][r] = best; pix[pp][r] = bi;
        }
    }
    __syncthreads();

    if (t == 0) {
        float cs[64]; int ci[64];
        #pragma unroll
        for (int i = 0; i < TKK; ++i)
            #pragma unroll
            for (int j = 0; j < TKK; ++j) {
                cs[i * TKK + j] = psc[0][i] + psc[1][j];
                ci[i * TKK + j] = pix[0][i] + pix[1][j] * NKK;
            }
        unsigned long long used = 0ull;
        float fs[TKK]; int fi[TKK];
        for (int r = 0; r < TKK; ++r) {
            float best = -3.4e38f; int bf = 0;
            for (int f = 0; f < 64; ++f)
                if (!((used >> f) & 1ull) && cs[f] > best) { best = cs[f]; bf = f; }
            used |= (1ull << bf);
            fs[r] = best; fi[r] = ci[bf];
        }
        float mx = fs[0];
        float e[TKK], sum = 0.f;
        for (int r = 0; r < TKK; ++r) { e[r] = expf(fs[r] - mx); sum += e[r]; }
        float inv = 1.f / sum;
        for (int r = 0; r < TKK; ++r) {
            wts[(long long)bid * TKK + r]  = e[r] * inv;
            idxs[(long long)bid * TKK + r] = fi[r] + h * NKV_;
        }
    }
}

// Weighted 8-row embedding-bag gather -> k,v in [B,H,S,D], bf16 out.
__global__ __launch_bounds__(256) void gather_kv(
    const float* __restrict__ ke, const float* __restrict__ ve,
    const float* __restrict__ wts, const int* __restrict__ idxs,
    bf16* __restrict__ kb, bf16* __restrict__ vb)
{
    int bid = blockIdx.x;                 // (b*S+s)*H + h
    int h = bid % HH;
    int bs = bid / HH;
    int b = bs / SS, s = bs % SS;

    float w[TKK]; int rix[TKK];
    #pragma unroll
    for (int t = 0; t < TKK; ++t) {
        w[t]   = wts[(long long)bid * TKK + t];
        rix[t] = idxs[(long long)bid * TKK + t];
    }
    int c0 = threadIdx.x * 4;
    float4 ak = {0.f,0.f,0.f,0.f}, av = {0.f,0.f,0.f,0.f};
    #pragma unroll
    for (int t = 0; t < TKK; ++t) {
        float4 kr = *(const float4*)&ke[(long long)rix[t] * DD + c0];
        float4 vr = *(const float4*)&ve[(long long)rix[t] * DD + c0];
        ak.x += w[t]*kr.x; ak.y += w[t]*kr.y; ak.z += w[t]*kr.z; ak.w += w[t]*kr.w;
        av.x += w[t]*vr.x; av.y += w[t]*vr.y; av.z += w[t]*vr.z; av.w += w[t]*vr.w;
    }
    long long off = ((long long)(b * HH + h) * SS + s) * DD + c0;
    ushort4 uk; uk.x=f2b(ak.x); uk.y=f2b(ak.y); uk.z=f2b(ak.z); uk.w=f2b(ak.w);
    ushort4 uv; uv.x=f2b(av.x); uv.y=f2b(av.y); uv.z=f2b(av.z); uv.w=f2b(av.w);
    *(ushort4*)&kb[off] = uk;
    *(ushort4*)&vb[off] = uv;
}

// 64x64 LDS transpose: vb [z][S][D] -> vt [z][D][S], bf16.
__global__ __launch_bounds__(256) void tr64(const bf16* __restrict__ src,
                                            bf16* __restrict__ dst)
{
    __shared__ unsigned short t[64][65];
    long long z = blockIdx.z;
    const unsigned short* s = (const unsigned short*)src + z * SS * DD;
    unsigned short* d = (unsigned short*)dst + z * DD * SS;
    int s0 = blockIdx.x * 64;             // S-block
    int d0 = blockIdx.y * 64;             // D-block
    int tid = threadIdx.x;
    int r = tid / 16, c4 = (tid % 16) * 4;
    #pragma unroll
    for (int i = 0; i < 4; ++i) {
        int sr = r + i * 16;
        ushort4 v = *(const ushort4*)&s[(long long)(s0 + sr) * DD + d0 + c4];
        t[sr][c4] = v.x; t[sr][c4+1] = v.y; t[sr][c4+2] = v.z; t[sr][c4+3] = v.w;
    }
    __syncthreads();
    #pragma unroll
    for (int i = 0; i < 4; ++i) {
        int dr = r + i * 16;              // D index
        ushort4 v;
        v.x = t[c4][dr]; v.y = t[c4+1][dr]; v.z = t[c4+2][dr]; v.w = t[c4+3][dr];
        *(ushort4*)&d[(long long)(d0 + dr) * SS + s0 + c4] = v;
    }
}

// Causal softmax on bf16 score rows; fp32 compute, writes entire row.
__global__ __launch_bounds__(256) void softmax_causal_bf(bf16* __restrict__ sc)
{
    int r  = blockIdx.x;                  // (b*H+h)*S + sq
    int sq = r % SS;
    unsigned short* row = (unsigned short*)(sc + (long long)r * SS);
    int t = threadIdx.x;
    int nvalid = sq + 1;

    float v[4];
    float lm = -INFINITY;
    #pragma unroll
    for (int i = 0; i < 4; ++i) {
        int j = t + i * 256;
        v[i] = (j < nvalid) ? b2f(row[j]) : -INFINITY;
        lm = fmaxf(lm, v[i]);
    }
    __shared__ float red[256];
    red[t] = lm; __syncthreads();
    for (int o = 128; o > 0; o >>= 1) {
        if (t < o) red[t] = fmaxf(red[t], red[t + o]);
        __syncthreads();
    }
    float m = red[0];
    __syncthreads();

    float e[4], ls = 0.f;
    #pragma unroll
    for (int i = 0; i < 4; ++i) {
        int j = t + i * 256;
        e[i] = (j < nvalid) ? expf(v[i] - m) : 0.f;
        ls += e[i];
    }
    red[t] = ls; __syncthreads();
    for (int o = 128; o > 0; o >>= 1) {
        if (t < o) red[t] += red[t + o];
        __syncthreads();
    }
    float inv = 1.f / red[0];
    #pragma unroll
    for (int i = 0; i < 4; ++i) row[t + i * 256] = f2b(e[i] * inv);
}

extern "C" void kernel_launch(void* const* d_in, const int* in_sizes, int n_in,
                              void* d_out, int out_size, void* d_ws, size_t ws_size,
                              hipStream_t stream)
{
    const float* inputs     = (const float*)d_in[0];
    const float* Wq         = (const float*)d_in[1];
    const float* Wpk        = (const float*)d_in[2];
    const float* pk_keys    = (const float*)d_in[3];
    const float* keys_emb   = (const float*)d_in[4];
    const float* values_emb = (const float*)d_in[5];
    const float* Wo         = (const float*)d_in[6];
    float* out = (float*)d_out;

    // ---- workspace layout (129 MB, aliased) ----
    const long long MB = 1LL << 20;
    char* base = (char*)d_ws;
    bf16* kb  = (bf16*)(base);            // [B,H,S,D]  32MB
    bf16* vb  = (bf16*)(base + 32*MB);    // [B,H,S,D]  32MB; later q / ctx slab
    bf16* vt  = (bf16*)(base + 64*MB);    // [B,H,D,S]  32MB
    char* screg = base + 96*MB;           // 32MB multi-use region
    bf16* scb = (bf16*)screg;             // scores [B*H,S,S] (steps 5-7)
    float* pqb = (float*)screg;           // [0:8MB)  pq fp32 (steps 1-2)
    bf16* Wqb  = (bf16*)(screg + 8*MB);   // [8:24MB) bf16 Wq (step 4)
    bf16* xb   = (bf16*)(screg + 24*MB);  // [24:28MB) bf16 inputs (step 4)
    bf16* Wob  = (bf16*)screg;            // [0:16MB) bf16 Wo (after step 7)
    float* wtb = (float*)(base + 128*MB); // routing weights fp32
    int*   ixb = (int*)(base + 128*MB + (512<<10));
    size_t needed = (size_t)(129*MB);
    if (ws_size < needed) return;

    bf16* qc  = vb;                       // q then ctx, [B,S,H*D] (vb dead after tr64)
    const long long SLAB = (long long)SS * HH * DD;     // 8,388,608
    const long long SD   = (long long)SS * DD;          // 1,048,576

    // 0. bf16 copies of inputs and Wq (into score region; dead before step 5)
    cvt_bf<<<dim3(2048), 256, 0, stream>>>(inputs, xb, 2097152LL);
    cvt_bf<<<dim3(8192), 256, 0, stream>>>(Wq, Wqb, 8388608LL);

    // 1. pq = inputs @ Wpk^T (fp32 — routing precision)
    gemm_f32t<<<dim3(16, 32, 1), 256, 0, stream>>>(inputs, Wpk, pqb);

    // 2. product-key routing -> fp32 weights + row indices
    pk_route<<<dim3(BB * SS * HH), 64, 0, stream>>>(pqb, pk_keys, wtb, ixb);

    // 3. weighted embedding gather -> k,v [B,H,S,D] bf16
    gather_kv<<<dim3(BB * SS * HH), 256, 0, stream>>>(
        keys_emb, values_emb, wtb, ixb, kb, vb);

    // 3b. v transpose: [B,H,S,D] -> [B,H,D,S]
    tr64<<<dim3(16, 16, BB * HH), 256, 0, stream>>>(vb, vt);

    // 4. q = (xb @ Wqb^T) * d^-0.5 -> qc [B,S,H*D] bf16   (vb slot now free)
    mgemm<bf16, 0><<<dim3(64, 16, 1), 256, 0, stream>>>(
        xb, Wqb, qc, 1024, 1024, 1024, 8192,
        0, 0, 0, 0, 0, 0, 1, 0.03125f);

    // 5. scores = q @ k^T per (b,h), causal tile-skip -> scb bf16
    mgemm<bf16, 1><<<dim3(8, 8, BB * HH), 256, 0, stream>>>(
        qc, kb, scb, 1024, 8192, 1024, 1024,
        SLAB, (long long)DD, (long long)HH * SD, SD,
        (long long)HH * SS * SS, (long long)SS * SS, HH, 1.0f);

    // 6. causal softmax (fp32 compute, bf16 store; writes full rows)
    softmax_causal_bf<<<dim3(BB * HH * SS), 256, 0, stream>>>(scb);

    // 7. ctx = att @ v  (B = vt, B^T form), K limited to row0+128; ctx -> qc slab
    mgemm<bf16, 2><<<dim3(8, 8, BB * HH), 256, 0, stream>>>(
        scb, vt, qc, 1024, 1024, 1024, 8192,
        (long long)HH * SS * SS, (long long)SS * SS,
        (long long)HH * SD, SD,
        SLAB, (long long)DD, HH, 1.0f);

    // 7b. bf16 Wo (scores dead now)
    cvt_bf<<<dim3(8192), 256, 0, stream>>>(Wo, Wob, 8388608LL);

    // 8. out = ctx @ Wo^T  (fp32 out)
    mgemm<float, 0><<<dim3(8, 16, 1), 256, 0, stream>>>(
        qc, Wob, out, 8192, 8192, 8192, 1024,
        0, 0, 0, 0, 0, 0, 1, 1.0f);
}

// Round 4
// 607.985 us; speedup vs baseline: 3.0771x; 1.1065x over previous
//
#include <hip/hip_runtime.h>
#include <hip/hip_bf16.h>

// Problem constants
#define BB   2
#define SS   1024
#define DD   1024
#define HH   8
#define NPP  2
#define NKK  32
#define DKK  64
#define TKK  8
#define NKV_ 1024

typedef __hip_bfloat16 bf16;
typedef __attribute__((ext_vector_type(8))) short bf16x8;
typedef __attribute__((ext_vector_type(4))) float f32x4;

using u32g = __attribute__((address_space(1))) unsigned int;
using u32l = __attribute__((address_space(3))) unsigned int;

// async global->LDS, 16B per lane; LDS dest = wave-uniform base + lane*16
#define GLDS16(g, l) __builtin_amdgcn_global_load_lds((const u32g*)(g), (u32l*)(l), 16, 0, 0)

// ---- scalar/vec conversion helpers ----
__device__ inline unsigned short f2b(float f) {       // RNE f32->bf16
    unsigned x = __float_as_uint(f);
    return (unsigned short)((x + 0x7fffu + ((x >> 16) & 1u)) >> 16);
}
__device__ inline float b2f(unsigned short u) {
    return __uint_as_float(((unsigned)u) << 16);
}

// fp32 -> bf16 convert, 4 elems/thread
__global__ __launch_bounds__(256) void cvt_bf(const float* __restrict__ src,
                                              bf16* __restrict__ dst, long long n)
{
    long long i = ((long long)blockIdx.x * 256 + threadIdx.x) * 4;
    if (i >= n) return;
    float4 v = *(const float4*)&src[i];
    ushort4 u; u.x = f2b(v.x); u.y = f2b(v.y); u.z = f2b(v.z); u.w = f2b(v.w);
    *(ushort4*)&dst[i] = u;
}

// ============================================================================
// MFMA bf16 GEMM (m97 structure + T2 XOR swizzle + T1 XCD swizzle):
//   C[m,n] = scale * sum_k A[m][k] * B[n][k]
// 128x128 tile, BK=64, 4 waves (2x2 of 64x64), mfma_f32_16x16x32_bf16.
// LDS layout: LDS(row, chunk) = global(row, chunk ^ (row&7)), 16B chunks —
// achieved by pre-swizzling the per-lane GLOBAL source (dest stays linear,
// rule #21), inverted on every ds_read. CAUSAL==1: skip tiles above diagonal.
// CAUSAL==2: Klim = row0+128. NOTE: launches must have gx*gy*gz % 8 == 0.
// ============================================================================
template<typename TC, int CAUSAL>
__global__ __launch_bounds__(256) void mgemm(
    const bf16* __restrict__ A, const bf16* __restrict__ B, TC* __restrict__ C,
    int K, int lda, int ldb, int ldc,
    long long sAb, long long sAh, long long sBb, long long sBh,
    long long sCb, long long sCh, int zH, float scale)
{
    // T1: chunked XCD swizzle over the full linear grid (bijective: nwg%8==0)
    int gx = gridDim.x, gy = gridDim.y;
    int nwg = gx * gy * gridDim.z;
    int hw  = (blockIdx.z * gy + blockIdx.y) * gx + blockIdx.x;
    int w   = (hw & 7) * (nwg >> 3) + (hw >> 3);
    int bx  = w % gx;
    int rem = w / gx;
    int by  = rem % gy;
    int z   = rem / gy;

    int zb = z / zH, zh = z % zH;
    A += (long long)zb * sAb + (long long)zh * sAh;
    B += (long long)zb * sBb + (long long)zh * sBh;
    C += (long long)zb * sCb + (long long)zh * sCh;

    int row0 = by * 128, col0 = bx * 128;
    if (CAUSAL == 1 && col0 > row0 + 127) return;
    int Klim = (CAUSAL == 2) ? min(K, row0 + 128) : K;

    __shared__ short sh[16384];          // As = [0:8192), Bs = [8192:16384)
    short* As = sh;
    short* Bs = sh + 8192;

    int tid = threadIdx.x, wave = tid >> 6, lane = tid & 63;
    int wr = wave >> 1, wc = wave & 1;       // wave's 64x64 quadrant
    int lr = lane & 15, lg = lane >> 4;      // frag row / k-group

    f32x4 zero = {0.f, 0.f, 0.f, 0.f};
    f32x4 acc[4][4];
    #pragma unroll
    for (int m = 0; m < 4; ++m)
        #pragma unroll
        for (int n = 0; n < 4; ++n) acc[m][n] = zero;

    // staging: wave stages 32 rows of A and B per K-step; one GLDS16 = 8 rows.
    // source chunk pre-swizzled: chunk ^= (row & 7), row&7 == lane>>3 here.
    int srow = wave * 32 + (lane >> 3);
    int scol = ((lane & 7) ^ (lane >> 3)) * 8;
    // frag-read swizzle: chunk(kk,lg) ^ (row&7), row&7 == lr&7
    int fo = (lg ^ (lr & 7)) * 8;            // kk=0 elem offset; kk=1 -> fo^32

    for (int k0 = 0; k0 < Klim; k0 += 64) {
        const bf16* Ak = A + (long long)(row0 + srow) * lda + k0 + scol;
        const bf16* Bk = B + (long long)(col0 + srow) * ldb + k0 + scol;
        #pragma unroll
        for (int i = 0; i < 4; ++i) {
            GLDS16(Ak + (long long)i * 8 * lda, &As[(wave * 32 + i * 8) * 64]);
            GLDS16(Bk + (long long)i * 8 * ldb, &Bs[(wave * 32 + i * 8) * 64]);
        }
        asm volatile("s_waitcnt vmcnt(0)" ::: "memory");
        __syncthreads();

        #pragma unroll
        for (int kk = 0; kk < 2; ++kk) {
            bf16x8 af[4], bfr[4];
            #pragma unroll
            for (int m = 0; m < 4; ++m)
                af[m] = *(const bf16x8*)&As[(wr * 64 + m * 16 + lr) * 64 + (fo ^ (kk * 32))];
            #pragma unroll
            for (int n = 0; n < 4; ++n)
                bfr[n] = *(const bf16x8*)&Bs[(wc * 64 + n * 16 + lr) * 64 + (fo ^ (kk * 32))];
            #pragma unroll
            for (int m = 0; m < 4; ++m)
                #pragma unroll
                for (int n = 0; n < 4; ++n)
                    acc[m][n] = __builtin_amdgcn_mfma_f32_16x16x32_bf16(
                        af[m], bfr[n], acc[m][n], 0, 0, 0);
        }
        __syncthreads();
    }

    // C/D layout: col = lane&15, row = (lane>>4)*4 + r  [m89-verified]
    if constexpr (sizeof(TC) == 2) {
        // bf16 out: stage quadrant in LDS (swizzled), then 16B coalesced stores
        short* cs = &sh[wave * 4096];        // 64x64 bf16 per-wave region
        #pragma unroll
        for (int m = 0; m < 4; ++m)
            #pragma unroll
            for (int n = 0; n < 4; ++n)
                #pragma unroll
                for (int r = 0; r < 4; ++r) {
                    int rl = m * 16 + lg * 4 + r;
                    int cc = (n * 2 + (lr >> 3)) ^ (rl & 7);
                    cs[rl * 64 + cc * 8 + (lr & 7)] =
                        (short)f2b(scale * acc[m][n][r]);
                }
        #pragma unroll
        for (int i = 0; i < 8; ++i) {
            int rl = i * 8 + (lane >> 3);
            int ch = (lane & 7) ^ (lane >> 3);
            bf16x8 v = *(const bf16x8*)&cs[rl * 64 + ch * 8];
            *(bf16x8*)&C[(long long)(row0 + wr * 64 + rl) * ldc
                         + col0 + wc * 64 + (lane & 7) * 8] = v;
        }
    } else {
        #pragma unroll
        for (int m = 0; m < 4; ++m) {
            int row = row0 + wr * 64 + m * 16 + lg * 4;
            #pragma unroll
            for (int n = 0; n < 4; ++n) {
                int col = col0 + wc * 64 + n * 16 + lr;
                #pragma unroll
                for (int r = 0; r < 4; ++r)
                    C[(long long)(row + r) * ldc + col] = scale * acc[m][n][r];
            }
        }
    }
}

// ============================================================================
// fp32 vector GEMM (routing projection only): C[m,n] = sum_k A[m][k]*B[n][k]
// ============================================================================
#define TILE 64
#define KT   16
#define LPAD 4
__global__ __launch_bounds__(256) void gemm_f32t(
    const float* __restrict__ A, const float* __restrict__ Bm, float* __restrict__ C)
{
    int row0 = blockIdx.y * TILE, col0 = blockIdx.x * TILE;
    __shared__ float As[KT][TILE + LPAD];
    __shared__ float Bs[KT][TILE + LPAD];
    int tid = threadIdx.x, tx = tid % 16, ty = tid / 16;
    float acc[4][4] = {{0.f}};
    int lr = tid / 4, lk = (tid % 4) * 4;

    for (int k0 = 0; k0 < 1024; k0 += KT) {
        float4 va = *(const float4*)&A[(long long)(row0 + lr) * 1024 + k0 + lk];
        As[lk + 0][lr] = va.x; As[lk + 1][lr] = va.y;
        As[lk + 2][lr] = va.z; As[lk + 3][lr] = va.w;
        float4 vb = *(const float4*)&Bm[(long long)(col0 + lr) * 1024 + k0 + lk];
        Bs[lk + 0][lr] = vb.x; Bs[lk + 1][lr] = vb.y;
        Bs[lk + 2][lr] = vb.z; Bs[lk + 3][lr] = vb.w;
        __syncthreads();
        #pragma unroll
        for (int kk = 0; kk < KT; ++kk) {
            float a[4], b[4];
            #pragma unroll
            for (int i = 0; i < 4; ++i) a[i] = As[kk][ty * 4 + i];
            #pragma unroll
            for (int j = 0; j < 4; ++j) b[j] = Bs[kk][tx * 4 + j];
            #pragma unroll
            for (int i = 0; i < 4; ++i)
                #pragma unroll
                for (int j = 0; j < 4; ++j)
                    acc[i][j] = fmaf(a[i], b[j], acc[i][j]);
        }
        __syncthreads();
    }
    #pragma unroll
    for (int i = 0; i < 4; ++i)
        *(float4*)&C[(long long)(row0 + ty * 4 + i) * 1024 + col0 + tx * 4] =
            make_float4(acc[i][0], acc[i][1], acc[i][2], acc[i][3]);
}

// Product-key routing: one 64-thread block per (b,s,h). jax.lax.top_k
// semantics: descending, ties -> lowest index. All fp32.
__global__ __launch_bounds__(64) void pk_route(
    const float* __restrict__ pq, const float* __restrict__ pkk,
    float* __restrict__ wts, int* __restrict__ idxs)
{
    int bid = blockIdx.x;                 // (b*S+s)*H + h
    int h   = bid % HH;
    long long bs = bid / HH;
    int t = threadIdx.x;
    int p = t >> 5, n = t & 31;

    const float* pv = pq  + (bs * NPP + p) * (HH * DKK) + h * DKK;
    const float* kv = pkk + ((long long)(p * NKK + n) * HH + h) * DKK;
    float s = 0.f;
    #pragma unroll 8
    for (int d = 0; d < DKK; ++d) s = fmaf(pv[d], kv[d], s);

    __shared__ float sim[64];
    __shared__ float psc[2][TKK];
    __shared__ int   pix[2][TKK];
    sim[t] = s;
    __syncthreads();

    if ((t & 31) == 0) {
        int pp = t >> 5;
        unsigned used = 0;
        for (int r = 0; r < TKK; ++r) {
            float best = -3.4e38f; int bi = 0;
            for (int m = 0; m < NKK; ++m) {
                float v = sim[pp * NKK + m];
                if (!((used >> m) & 1u) && v > best) { best = v; bi = m; }
            }
            used |= (1u << bi);
            psc[pp][r] = best; pix[pp][r] = bi;
        }
    }
    __syncthreads();

    if (t == 0) {
        float cs[64]; int ci[64];
        #pragma unroll
        for (int i = 0; i < TKK; ++i)
            #pragma unroll
            for (int j = 0; j < TKK; ++j) {
                cs[i * TKK + j] = psc[0][i] + psc[1][j];
                ci[i * TKK + j] = pix[0][i] + pix[1][j] * NKK;
            }
        unsigned long long used = 0ull;
        float fs[TKK]; int fi[TKK];
        for (int r = 0; r < TKK; ++r) {
            float best = -3.4e38f; int bf = 0;
            for (int f = 0; f < 64; ++f)
                if (!((used >> f) & 1ull) && cs[f] > best) { best = cs[f]; bf = f; }
            used |= (1ull << bf);
            fs[r] = best; fi[r] = ci[bf];
        }
        float mx = fs[0];
        float e[TKK], sum = 0.f;
        for (int r = 0; r < TKK; ++r) { e[r] = expf(fs[r] - mx); sum += e[r]; }
        float inv = 1.f / sum;
        for (int r = 0; r < TKK; ++r) {
            wts[(long long)bid * TKK + r]  = e[r] * inv;
            idxs[(long long)bid * TKK + r] = fi[r] + h * NKV_;
        }
    }
}

// Weighted 8-row embedding-bag gather -> k,v in [B,H,S,D], bf16 out.
__global__ __launch_bounds__(256) void gather_kv(
    const float* __restrict__ ke, const float* __restrict__ ve,
    const float* __restrict__ wts, const int* __restrict__ idxs,
    bf16* __restrict__ kb, bf16* __restrict__ vb)
{
    int bid = blockIdx.x;                 // (b*S+s)*H + h
    int h = bid % HH;
    int bs = bid / HH;
    int b = bs / SS, s = bs % SS;

    float w[TKK]; int rix[TKK];
    #pragma unroll
    for (int t = 0; t < TKK; ++t) {
        w[t]   = wts[(long long)bid * TKK + t];
        rix[t] = idxs[(long long)bid * TKK + t];
    }
    int c0 = threadIdx.x * 4;
    float4 ak = {0.f,0.f,0.f,0.f}, av = {0.f,0.f,0.f,0.f};
    #pragma unroll
    for (int t = 0; t < TKK; ++t) {
        float4 kr = *(const float4*)&ke[(long long)rix[t] * DD + c0];
        float4 vr = *(const float4*)&ve[(long long)rix[t] * DD + c0];
        ak.x += w[t]*kr.x; ak.y += w[t]*kr.y; ak.z += w[t]*kr.z; ak.w += w[t]*kr.w;
        av.x += w[t]*vr.x; av.y += w[t]*vr.y; av.z += w[t]*vr.z; av.w += w[t]*vr.w;
    }
    long long off = ((long long)(b * HH + h) * SS + s) * DD + c0;
    ushort4 uk; uk.x=f2b(ak.x); uk.y=f2b(ak.y); uk.z=f2b(ak.z); uk.w=f2b(ak.w);
    ushort4 uv; uv.x=f2b(av.x); uv.y=f2b(av.y); uv.z=f2b(av.z); uv.w=f2b(av.w);
    *(ushort4*)&kb[off] = uk;
    *(ushort4*)&vb[off] = uv;
}

// 64x64 LDS transpose: vb [z][S][D] -> vt [z][D][S], bf16.
__global__ __launch_bounds__(256) void tr64(const bf16* __restrict__ src,
                                            bf16* __restrict__ dst)
{
    __shared__ unsigned short t[64][65];
    long long z = blockIdx.z;
    const unsigned short* s = (const unsigned short*)src + z * SS * DD;
    unsigned short* d = (unsigned short*)dst + z * DD * SS;
    int s0 = blockIdx.x * 64;             // S-block
    int d0 = blockIdx.y * 64;             // D-block
    int tid = threadIdx.x;
    int r = tid / 16, c4 = (tid % 16) * 4;
    #pragma unroll
    for (int i = 0; i < 4; ++i) {
        int sr = r + i * 16;
        ushort4 v = *(const ushort4*)&s[(long long)(s0 + sr) * DD + d0 + c4];
        t[sr][c4] = v.x; t[sr][c4+1] = v.y; t[sr][c4+2] = v.z; t[sr][c4+3] = v.w;
    }
    __syncthreads();
    #pragma unroll
    for (int i = 0; i < 4; ++i) {
        int dr = r + i * 16;              // D index
        ushort4 v;
        v.x = t[c4][dr]; v.y = t[c4+1][dr]; v.z = t[c4+2][dr]; v.w = t[c4+3][dr];
        *(ushort4*)&d[(long long)(d0 + dr) * SS + s0 + c4] = v;
    }
}

// Causal softmax on bf16 score rows; fp32 compute, writes entire row.
__global__ __launch_bounds__(256) void softmax_causal_bf(bf16* __restrict__ sc)
{
    int r  = blockIdx.x;                  // (b*H+h)*S + sq
    int sq = r % SS;
    unsigned short* row = (unsigned short*)(sc + (long long)r * SS);
    int t = threadIdx.x;
    int nvalid = sq + 1;

    float v[4];
    float lm = -INFINITY;
    #pragma unroll
    for (int i = 0; i < 4; ++i) {
        int j = t + i * 256;
        v[i] = (j < nvalid) ? b2f(row[j]) : -INFINITY;
        lm = fmaxf(lm, v[i]);
    }
    __shared__ float red[256];
    red[t] = lm; __syncthreads();
    for (int o = 128; o > 0; o >>= 1) {
        if (t < o) red[t] = fmaxf(red[t], red[t + o]);
        __syncthreads();
    }
    float m = red[0];
    __syncthreads();

    float e[4], ls = 0.f;
    #pragma unroll
    for (int i = 0; i < 4; ++i) {
        int j = t + i * 256;
        e[i] = (j < nvalid) ? expf(v[i] - m) : 0.f;
        ls += e[i];
    }
    red[t] = ls; __syncthreads();
    for (int o = 128; o > 0; o >>= 1) {
        if (t < o) red[t] += red[t + o];
        __syncthreads();
    }
    float inv = 1.f / red[0];
    #pragma unroll
    for (int i = 0; i < 4; ++i) row[t + i * 256] = f2b(e[i] * inv);
}

extern "C" void kernel_launch(void* const* d_in, const int* in_sizes, int n_in,
                              void* d_out, int out_size, void* d_ws, size_t ws_size,
                              hipStream_t stream)
{
    const float* inputs     = (const float*)d_in[0];
    const float* Wq         = (const float*)d_in[1];
    const float* Wpk        = (const float*)d_in[2];
    const float* pk_keys    = (const float*)d_in[3];
    const float* keys_emb   = (const float*)d_in[4];
    const float* values_emb = (const float*)d_in[5];
    const float* Wo         = (const float*)d_in[6];
    float* out = (float*)d_out;

    // ---- workspace layout (129 MB, aliased) ----
    const long long MB = 1LL << 20;
    char* base = (char*)d_ws;
    bf16* kb  = (bf16*)(base);            // [B,H,S,D]  32MB
    bf16* vb  = (bf16*)(base + 32*MB);    // [B,H,S,D]  32MB; later q / ctx slab
    bf16* vt  = (bf16*)(base + 64*MB);    // [B,H,D,S]  32MB
    char* screg = base + 96*MB;           // 32MB multi-use region
    bf16* scb = (bf16*)screg;             // scores [B*H,S,S] (steps 5-7)
    float* pqb = (float*)screg;           // [0:8MB)  pq fp32 (steps 1-2)
    bf16* Wqb  = (bf16*)(screg + 8*MB);   // [8:24MB) bf16 Wq (step 4)
    bf16* xb   = (bf16*)(screg + 24*MB);  // [24:28MB) bf16 inputs (step 4)
    bf16* Wob  = (bf16*)screg;            // [0:16MB) bf16 Wo (after step 7)
    float* wtb = (float*)(base + 128*MB); // routing weights fp32
    int*   ixb = (int*)(base + 128*MB + (512<<10));
    size_t needed = (size_t)(129*MB);
    if (ws_size < needed) return;

    bf16* qc  = vb;                       // q then ctx, [B,S,H*D] (vb dead after tr64)
    const long long SLAB = (long long)SS * HH * DD;     // 8,388,608
    const long long SD   = (long long)SS * DD;          // 1,048,576

    // 0. bf16 copies of inputs and Wq (into score region; dead before step 5)
    cvt_bf<<<dim3(2048), 256, 0, stream>>>(inputs, xb, 2097152LL);
    cvt_bf<<<dim3(8192), 256, 0, stream>>>(Wq, Wqb, 8388608LL);

    // 1. pq = inputs @ Wpk^T (fp32 — routing precision)
    gemm_f32t<<<dim3(16, 32, 1), 256, 0, stream>>>(inputs, Wpk, pqb);

    // 2. product-key routing -> fp32 weights + row indices
    pk_route<<<dim3(BB * SS * HH), 64, 0, stream>>>(pqb, pk_keys, wtb, ixb);

    // 3. weighted embedding gather -> k,v [B,H,S,D] bf16
    gather_kv<<<dim3(BB * SS * HH), 256, 0, stream>>>(
        keys_emb, values_emb, wtb, ixb, kb, vb);

    // 3b. v transpose: [B,H,S,D] -> [B,H,D,S]
    tr64<<<dim3(16, 16, BB * HH), 256, 0, stream>>>(vb, vt);

    // 4. q = (xb @ Wqb^T) * d^-0.5 -> qc [B,S,H*D] bf16   (vb slot now free)
    mgemm<bf16, 0><<<dim3(64, 16, 1), 256, 0, stream>>>(
        xb, Wqb, qc, 1024, 1024, 1024, 8192,
        0, 0, 0, 0, 0, 0, 1, 0.03125f);

    // 5. scores = q @ k^T per (b,h), causal tile-skip -> scb bf16
    mgemm<bf16, 1><<<dim3(8, 8, BB * HH), 256, 0, stream>>>(
        qc, kb, scb, 1024, 8192, 1024, 1024,
        SLAB, (long long)DD, (long long)HH * SD, SD,
        (long long)HH * SS * SS, (long long)SS * SS, HH, 1.0f);

    // 6. causal softmax (fp32 compute, bf16 store; writes full rows)
    softmax_causal_bf<<<dim3(BB * HH * SS), 256, 0, stream>>>(scb);

    // 7. ctx = att @ v  (B = vt, B^T form), K limited to row0+128; ctx -> qc slab
    mgemm<bf16, 2><<<dim3(8, 8, BB * HH), 256, 0, stream>>>(
        scb, vt, qc, 1024, 1024, 1024, 8192,
        (long long)HH * SS * SS, (long long)SS * SS,
        (long long)HH * SD, SD,
        SLAB, (long long)DD, HH, 1.0f);

    // 7b. bf16 Wo (scores dead now)
    cvt_bf<<<dim3(8192), 256, 0, stream>>>(Wo, Wob, 8388608LL);

    // 8. out = ctx @ Wo^T  (fp32 out)
    mgemm<float, 0><<<dim3(8, 16, 1), 256, 0, stream>>>(
        qc, Wob, out, 8192, 8192, 8192, 1024,
        0, 0, 0, 0, 0, 0, 1, 1.0f);
}

// Round 5
// 516.736 us; speedup vs baseline: 3.6205x; 1.1766x over previous
//
#include <hip/hip_runtime.h>
#include <hip/hip_bf16.h>

// Problem constants
#define BB   2
#define SS   1024
#define DD   1024
#define HH   8
#define NPP  2
#define NKK  32
#define DKK  64
#define TKK  8
#define NKV_ 1024

typedef __hip_bfloat16 bf16;
typedef __attribute__((ext_vector_type(8))) short bf16x8;
typedef __attribute__((ext_vector_type(4))) float f32x4;

using u32g = __attribute__((address_space(1))) unsigned int;
using u32l = __attribute__((address_space(3))) unsigned int;

// async global->LDS, 16B per lane; LDS dest = wave-uniform base + lane*16
#define GLDS16(g, l) __builtin_amdgcn_global_load_lds((const u32g*)(g), (u32l*)(l), 16, 0, 0)

// ---- scalar/vec conversion helpers ----
__device__ inline unsigned short f2b(float f) {       // RNE f32->bf16
    unsigned x = __float_as_uint(f);
    return (unsigned short)((x + 0x7fffu + ((x >> 16) & 1u)) >> 16);
}
__device__ inline float b2f(unsigned short u) {
    return __uint_as_float(((unsigned)u) << 16);
}

// fp32 -> bf16 convert, 4 elems/thread
__global__ __launch_bounds__(256) void cvt_bf(const float* __restrict__ src,
                                              bf16* __restrict__ dst, long long n)
{
    long long i = ((long long)blockIdx.x * 256 + threadIdx.x) * 4;
    if (i >= n) return;
    float4 v = *(const float4*)&src[i];
    ushort4 u; u.x = f2b(v.x); u.y = f2b(v.y); u.z = f2b(v.z); u.w = f2b(v.w);
    *(ushort4*)&dst[i] = u;
}

// ============================================================================
// MFMA bf16 GEMM (m97 structure + T2 XOR swizzle + T1 XCD swizzle):
//   C[m,n] = scale * sum_k A[m][k] * B[n][k]
// 128x128 tile, BK=64, 4 waves (2x2 of 64x64), mfma_f32_16x16x32_bf16.
// LDS(row, chunk) = global(row, chunk ^ (row&7)), 16B chunks (rule #21:
// pre-swizzled global source, linear LDS dest, same XOR on ds_read).
// CAUSAL==1: skip tiles above diagonal. CAUSAL==2: Klim = row0+128.
// NOTE: launches must have gx*gy*gz % 8 == 0.
// ============================================================================
template<typename TC, int CAUSAL>
__global__ __launch_bounds__(256) void mgemm(
    const bf16* __restrict__ A, const bf16* __restrict__ B, TC* __restrict__ C,
    int K, int lda, int ldb, int ldc,
    long long sAb, long long sAh, long long sBb, long long sBh,
    long long sCb, long long sCh, int zH, float scale)
{
    // T1: chunked XCD swizzle over the full linear grid (bijective: nwg%8==0)
    int gx = gridDim.x, gy = gridDim.y;
    int nwg = gx * gy * gridDim.z;
    int hw  = (blockIdx.z * gy + blockIdx.y) * gx + blockIdx.x;
    int w   = (hw & 7) * (nwg >> 3) + (hw >> 3);
    int bx  = w % gx;
    int rem = w / gx;
    int by  = rem % gy;
    int z   = rem / gy;

    int zb = z / zH, zh = z % zH;
    A += (long long)zb * sAb + (long long)zh * sAh;
    B += (long long)zb * sBb + (long long)zh * sBh;
    C += (long long)zb * sCb + (long long)zh * sCh;

    int row0 = by * 128, col0 = bx * 128;
    if (CAUSAL == 1 && col0 > row0 + 127) return;
    int Klim = (CAUSAL == 2) ? min(K, row0 + 128) : K;

    __shared__ short sh[16384];          // As = [0:8192), Bs = [8192:16384)
    short* As = sh;
    short* Bs = sh + 8192;

    int tid = threadIdx.x, wave = tid >> 6, lane = tid & 63;
    int wr = wave >> 1, wc = wave & 1;       // wave's 64x64 quadrant
    int lr = lane & 15, lg = lane >> 4;      // frag row / k-group

    f32x4 zero = {0.f, 0.f, 0.f, 0.f};
    f32x4 acc[4][4];
    #pragma unroll
    for (int m = 0; m < 4; ++m)
        #pragma unroll
        for (int n = 0; n < 4; ++n) acc[m][n] = zero;

    // staging: wave stages 32 rows of A and B per K-step; one GLDS16 = 8 rows.
    int srow = wave * 32 + (lane >> 3);
    int scol = ((lane & 7) ^ (lane >> 3)) * 8;
    int fo = (lg ^ (lr & 7)) * 8;            // frag-read swizzle; kk=1 -> fo^32

    for (int k0 = 0; k0 < Klim; k0 += 64) {
        const bf16* Ak = A + (long long)(row0 + srow) * lda + k0 + scol;
        const bf16* Bk = B + (long long)(col0 + srow) * ldb + k0 + scol;
        #pragma unroll
        for (int i = 0; i < 4; ++i) {
            GLDS16(Ak + (long long)i * 8 * lda, &As[(wave * 32 + i * 8) * 64]);
            GLDS16(Bk + (long long)i * 8 * ldb, &Bs[(wave * 32 + i * 8) * 64]);
        }
        asm volatile("s_waitcnt vmcnt(0)" ::: "memory");
        __syncthreads();

        #pragma unroll
        for (int kk = 0; kk < 2; ++kk) {
            bf16x8 af[4], bfr[4];
            #pragma unroll
            for (int m = 0; m < 4; ++m)
                af[m] = *(const bf16x8*)&As[(wr * 64 + m * 16 + lr) * 64 + (fo ^ (kk * 32))];
            #pragma unroll
            for (int n = 0; n < 4; ++n)
                bfr[n] = *(const bf16x8*)&Bs[(wc * 64 + n * 16 + lr) * 64 + (fo ^ (kk * 32))];
            #pragma unroll
            for (int m = 0; m < 4; ++m)
                #pragma unroll
                for (int n = 0; n < 4; ++n)
                    acc[m][n] = __builtin_amdgcn_mfma_f32_16x16x32_bf16(
                        af[m], bfr[n], acc[m][n], 0, 0, 0);
        }
        __syncthreads();
    }

    // C/D layout: col = lane&15, row = (lane>>4)*4 + r  [m89-verified]
    if constexpr (sizeof(TC) == 2) {
        // bf16 out: stage quadrant in LDS (swizzled), then 16B coalesced stores
        short* cs = &sh[wave * 4096];        // 64x64 bf16 per-wave region
        #pragma unroll
        for (int m = 0; m < 4; ++m)
            #pragma unroll
            for (int n = 0; n < 4; ++n)
                #pragma unroll
                for (int r = 0; r < 4; ++r) {
                    int rl = m * 16 + lg * 4 + r;
                    int cc = (n * 2 + (lr >> 3)) ^ (rl & 7);
                    cs[rl * 64 + cc * 8 + (lr & 7)] =
                        (short)f2b(scale * acc[m][n][r]);
                }
        #pragma unroll
        for (int i = 0; i < 8; ++i) {
            int rl = i * 8 + (lane >> 3);
            int ch = (lane & 7) ^ (lane >> 3);
            bf16x8 v = *(const bf16x8*)&cs[rl * 64 + ch * 8];
            *(bf16x8*)&C[(long long)(row0 + wr * 64 + rl) * ldc
                         + col0 + wc * 64 + (lane & 7) * 8] = v;
        }
    } else {
        #pragma unroll
        for (int m = 0; m < 4; ++m) {
            int row = row0 + wr * 64 + m * 16 + lg * 4;
            #pragma unroll
            for (int n = 0; n < 4; ++n) {
                int col = col0 + wc * 64 + n * 16 + lr;
                #pragma unroll
                for (int r = 0; r < 4; ++r)
                    C[(long long)(row + r) * ldc + col] = scale * acc[m][n][r];
            }
        }
    }
}

// ============================================================================
// pq fixup: exact-fp32 recompute of pq rows for s < 64 (both batches).
// C[row, n] = sum_k A[row][k] * B[n][k]; row = z*1024 + (0..63).
// Routing index-selection is only output-sensitive at small s (causal
// attention concentrates there) — everywhere else bf16 pq is safe.
// ============================================================================
#define TILE 64
#define KT   16
#define LPAD 4
__global__ __launch_bounds__(256) void pq_fix(
    const float* __restrict__ A, const float* __restrict__ Bm, float* __restrict__ C)
{
    long long zo = (long long)blockIdx.z * 1024 * 1024;   // per-batch row offset
    A += zo; C += zo;
    int col0 = blockIdx.x * TILE;
    __shared__ float As[KT][TILE + LPAD];
    __shared__ float Bs[KT][TILE + LPAD];
    int tid = threadIdx.x, tx = tid % 16, ty = tid / 16;
    float acc[4][4] = {{0.f}};
    int lr = tid / 4, lk = (tid % 4) * 4;

    for (int k0 = 0; k0 < 1024; k0 += KT) {
        float4 va = *(const float4*)&A[(long long)lr * 1024 + k0 + lk];
        As[lk + 0][lr] = va.x; As[lk + 1][lr] = va.y;
        As[lk + 2][lr] = va.z; As[lk + 3][lr] = va.w;
        float4 vb = *(const float4*)&Bm[(long long)(col0 + lr) * 1024 + k0 + lk];
        Bs[lk + 0][lr] = vb.x; Bs[lk + 1][lr] = vb.y;
        Bs[lk + 2][lr] = vb.z; Bs[lk + 3][lr] = vb.w;
        __syncthreads();
        #pragma unroll
        for (int kk = 0; kk < KT; ++kk) {
            float a[4], b[4];
            #pragma unroll
            for (int i = 0; i < 4; ++i) a[i] = As[kk][ty * 4 + i];
            #pragma unroll
            for (int j = 0; j < 4; ++j) b[j] = Bs[kk][tx * 4 + j];
            #pragma unroll
            for (int i = 0; i < 4; ++i)
                #pragma unroll
                for (int j = 0; j < 4; ++j)
                    acc[i][j] = fmaf(a[i], b[j], acc[i][j]);
        }
        __syncthreads();
    }
    #pragma unroll
    for (int i = 0; i < 4; ++i)
        *(float4*)&C[(long long)(ty * 4 + i) * 1024 + col0 + tx * 4] =
            make_float4(acc[i][0], acc[i][1], acc[i][2], acc[i][3]);
}

// ============================================================================
// Product-key routing, wave-parallel (1 wave per (b,s,h), 4 waves/block).
// jax.lax.top_k semantics: descending, ties -> lowest index. fp32 scores.
// Stage 1: per-space top-8 of 32 via 8 rounds of 32-wide shfl_xor argmax.
// Stage 2: 64 combination candidates live one-per-lane (f = i*8+j = lane);
//          top-8 of 64 via 8 rounds of 64-wide argmax. Softmax via lane<8.
// ============================================================================
__global__ __launch_bounds__(256) void pk_route(
    const float* __restrict__ pq, const float* __restrict__ pkk,
    float* __restrict__ wts, int* __restrict__ idxs)
{
    int bid  = blockIdx.x * 4 + (threadIdx.x >> 6);   // (b*S+s)*H + h
    int lane = threadIdx.x & 63;
    int h    = bid % HH;
    long long bs = bid / HH;
    int p = lane >> 5, n = lane & 31;

    const float* pv = pq  + (bs * NPP + p) * (HH * DKK) + h * DKK;
    const float* kv = pkk + ((long long)(p * NKK + n) * HH + h) * DKK;
    float s = 0.f;
    #pragma unroll
    for (int d = 0; d < DKK; d += 4) {
        float4 q4 = *(const float4*)&pv[d];
        float4 k4 = *(const float4*)&kv[d];
        s = fmaf(q4.x, k4.x, fmaf(q4.y, k4.y, fmaf(q4.z, k4.z, fmaf(q4.w, k4.w, s))));
    }

    // ---- stage 1: top-8 of 32 within each half (p=0: lanes 0-31, p=1: 32-63)
    float myv = s;
    float keepv = 0.f; int keepn = 0;     // lane r (n==r, r<8) holds rank-r
    #pragma unroll
    for (int r = 0; r < TKK; ++r) {
        float bv = myv; int bn = n;
        #pragma unroll
        for (int off = 1; off < 32; off <<= 1) {
            float ov = __shfl_xor(bv, off);
            int   on = __shfl_xor(bn, off);
            if (ov > bv || (ov == bv && on < bn)) { bv = ov; bn = on; }
        }
        if (n == r) { keepv = bv; keepn = bn; }
        if (n == bn) myv = -INFINITY;     // mask this half's winner
    }

    // ---- stage 2: combine; lane f = i*8+j holds psc0[i]+psc1[j]
    int ci = lane >> 3, cj = lane & 7;
    float c0 = __shfl(keepv, ci);         // half-0 rank-ci
    int   n0 = __shfl(keepn, ci);
    float c1 = __shfl(keepv, 32 + cj);    // half-1 rank-cj
    int   n1 = __shfl(keepn, 32 + cj);
    float cv = c0 + c1;
    int cidx = n0 + n1 * NKK;

    float myc = cv;
    float fsv = 0.f; int fsi = 0;         // lane r<8 holds final rank-r
    float m0 = 0.f;
    #pragma unroll
    for (int r = 0; r < TKK; ++r) {
        float bv = myc; int bf = lane;
        #pragma unroll
        for (int off = 1; off < 64; off <<= 1) {
            float ov = __shfl_xor(bv, off);
            int   of = __shfl_xor(bf, off);
            if (ov > bv || (ov == bv && of < bf)) { bv = ov; bf = of; }
        }
        if (r == 0) m0 = bv;
        int widx = __shfl(cidx, bf);
        if (lane == r) { fsv = bv; fsi = widx; }
        if (lane == bf) myc = -INFINITY;
    }

    // ---- softmax over the 8 winners (lanes 0..7)
    float e = (lane < TKK) ? expf(fsv - m0) : 0.f;
    float sum = e;
    #pragma unroll
    for (int off = 1; off < 8; off <<= 1) sum += __shfl_xor(sum, off);
    if (lane < TKK) {
        wts[(long long)bid * TKK + lane]  = e / sum;
        idxs[(long long)bid * TKK + lane] = fsi + h * NKV_;
    }
}

// Weighted 8-row embedding-bag gather -> k,v in [B,H,S,D], bf16 out.
__global__ __launch_bounds__(256) void gather_kv(
    const float* __restrict__ ke, const float* __restrict__ ve,
    const float* __restrict__ wts, const int* __restrict__ idxs,
    bf16* __restrict__ kb, bf16* __restrict__ vb)
{
    int bid = blockIdx.x;                 // (b*S+s)*H + h
    int h = bid % HH;
    int bs = bid / HH;
    int b = bs / SS, s = bs % SS;

    float w[TKK]; int rix[TKK];
    #pragma unroll
    for (int t = 0; t < TKK; ++t) {
        w[t]   = wts[(long long)bid * TKK + t];
        rix[t] = idxs[(long long)bid * TKK + t];
    }
    int c0 = threadIdx.x * 4;
    float4 ak = {0.f,0.f,0.f,0.f}, av = {0.f,0.f,0.f,0.f};
    #pragma unroll
    for (int t = 0; t < TKK; ++t) {
        float4 kr = *(const float4*)&ke[(long long)rix[t] * DD + c0];
        float4 vr = *(const float4*)&ve[(long long)rix[t] * DD + c0];
        ak.x += w[t]*kr.x; ak.y += w[t]*kr.y; ak.z += w[t]*kr.z; ak.w += w[t]*kr.w;
        av.x += w[t]*vr.x; av.y += w[t]*vr.y; av.z += w[t]*vr.z; av.w += w[t]*vr.w;
    }
    long long off = ((long long)(b * HH + h) * SS + s) * DD + c0;
    ushort4 uk; uk.x=f2b(ak.x); uk.y=f2b(ak.y); uk.z=f2b(ak.z); uk.w=f2b(ak.w);
    ushort4 uv; uv.x=f2b(av.x); uv.y=f2b(av.y); uv.z=f2b(av.z); uv.w=f2b(av.w);
    *(ushort4*)&kb[off] = uk;
    *(ushort4*)&vb[off] = uv;
}

// 64x64 LDS transpose: vb [z][S][D] -> vt [z][D][S], bf16.
__global__ __launch_bounds__(256) void tr64(const bf16* __restrict__ src,
                                            bf16* __restrict__ dst)
{
    __shared__ unsigned short t[64][65];
    long long z = blockIdx.z;
    const unsigned short* s = (const unsigned short*)src + z * SS * DD;
    unsigned short* d = (unsigned short*)dst + z * DD * SS;
    int s0 = blockIdx.x * 64;             // S-block
    int d0 = blockIdx.y * 64;             // D-block
    int tid = threadIdx.x;
    int r = tid / 16, c4 = (tid % 16) * 4;
    #pragma unroll
    for (int i = 0; i < 4; ++i) {
        int sr = r + i * 16;
        ushort4 v = *(const ushort4*)&s[(long long)(s0 + sr) * DD + d0 + c4];
        t[sr][c4] = v.x; t[sr][c4+1] = v.y; t[sr][c4+2] = v.z; t[sr][c4+3] = v.w;
    }
    __syncthreads();
    #pragma unroll
    for (int i = 0; i < 4; ++i) {
        int dr = r + i * 16;              // D index
        ushort4 v;
        v.x = t[c4][dr]; v.y = t[c4+1][dr]; v.z = t[c4+2][dr]; v.w = t[c4+3][dr];
        *(ushort4*)&d[(long long)(d0 + dr) * SS + s0 + c4] = v;
    }
}

// Causal softmax on bf16 score rows; fp32 compute, writes entire row.
__global__ __launch_bounds__(256) void softmax_causal_bf(bf16* __restrict__ sc)
{
    int r  = blockIdx.x;                  // (b*H+h)*S + sq
    int sq = r % SS;
    unsigned short* row = (unsigned short*)(sc + (long long)r * SS);
    int t = threadIdx.x;
    int nvalid = sq + 1;

    float v[4];
    float lm = -INFINITY;
    #pragma unroll
    for (int i = 0; i < 4; ++i) {
        int j = t + i * 256;
        v[i] = (j < nvalid) ? b2f(row[j]) : -INFINITY;
        lm = fmaxf(lm, v[i]);
    }
    __shared__ float red[256];
    red[t] = lm; __syncthreads();
    for (int o = 128; o > 0; o >>= 1) {
        if (t < o) red[t] = fmaxf(red[t], red[t + o]);
        __syncthreads();
    }
    float m = red[0];
    __syncthreads();

    float e[4], ls = 0.f;
    #pragma unroll
    for (int i = 0; i < 4; ++i) {
        int j = t + i * 256;
        e[i] = (j < nvalid) ? expf(v[i] - m) : 0.f;
        ls += e[i];
    }
    red[t] = ls; __syncthreads();
    for (int o = 128; o > 0; o >>= 1) {
        if (t < o) red[t] += red[t + o];
        __syncthreads();
    }
    float inv = 1.f / red[0];
    #pragma unroll
    for (int i = 0; i < 4; ++i) row[t + i * 256] = f2b(e[i] * inv);
}

extern "C" void kernel_launch(void* const* d_in, const int* in_sizes, int n_in,
                              void* d_out, int out_size, void* d_ws, size_t ws_size,
                              hipStream_t stream)
{
    const float* inputs     = (const float*)d_in[0];
    const float* Wq         = (const float*)d_in[1];
    const float* Wpk        = (const float*)d_in[2];
    const float* pk_keys    = (const float*)d_in[3];
    const float* keys_emb   = (const float*)d_in[4];
    const float* values_emb = (const float*)d_in[5];
    const float* Wo         = (const float*)d_in[6];
    float* out = (float*)d_out;

    // ---- workspace layout (129 MB, aliased) ----
    const long long MB = 1LL << 20;
    char* base = (char*)d_ws;
    bf16* kb  = (bf16*)(base);            // [B,H,S,D]  32MB
    bf16* vb  = (bf16*)(base + 32*MB);    // [B,H,S,D]  32MB; later q / ctx slab
    bf16* vt  = (bf16*)(base + 64*MB);    // [B,H,D,S]  32MB
    char* screg = base + 96*MB;           // 32MB multi-use region
    bf16* scb = (bf16*)screg;             // scores [B*H,S,S] (steps 5-7)
    float* pqb = (float*)screg;           // [0:8MB)   pq fp32 (steps 1-2)
    bf16* Wpkb = (bf16*)(screg + 8*MB);   // [8:10MB)  bf16 Wpk (step 1)
    bf16* Wqb  = (bf16*)(screg + 10*MB);  // [10:26MB) bf16 Wq (step 4)
    bf16* xb   = (bf16*)(screg + 26*MB);  // [26:30MB) bf16 inputs (steps 1,4)
    bf16* Wob  = (bf16*)screg;            // [0:16MB)  bf16 Wo (after step 7)
    float* wtb = (float*)(base + 128*MB); // routing weights fp32
    int*   ixb = (int*)(base + 128*MB + (512<<10));
    size_t needed = (size_t)(129*MB);
    if (ws_size < needed) return;

    bf16* qc  = vb;                       // q then ctx, [B,S,H*D] (vb dead after tr64)
    const long long SLAB = (long long)SS * HH * DD;     // 8,388,608
    const long long SD   = (long long)SS * DD;          // 1,048,576

    // 0. bf16 copies of inputs, Wpk, Wq (into score region; dead before step 5)
    cvt_bf<<<dim3(2048), 256, 0, stream>>>(inputs, xb, 2097152LL);
    cvt_bf<<<dim3(1024), 256, 0, stream>>>(Wpk, Wpkb, 1048576LL);
    cvt_bf<<<dim3(8192), 256, 0, stream>>>(Wq, Wqb, 8388608LL);

    // 1. pq = xb @ Wpkb^T via MFMA (fp32 out) ...
    mgemm<float, 0><<<dim3(8, 16, 1), 256, 0, stream>>>(
        xb, Wpkb, pqb, 1024, 1024, 1024, 1024,
        0, 0, 0, 0, 0, 0, 1, 1.0f);

    // 1b. ... then exact-fp32 fixup of rows s<64 (both batches)
    pq_fix<<<dim3(16, 1, 2), 256, 0, stream>>>(inputs, Wpk, pqb);

    // 2. product-key routing -> fp32 weights + row indices (wave-parallel)
    pk_route<<<dim3(BB * SS * HH / 4), 256, 0, stream>>>(pqb, pk_keys, wtb, ixb);

    // 3. weighted embedding gather -> k,v [B,H,S,D] bf16
    gather_kv<<<dim3(BB * SS * HH), 256, 0, stream>>>(
        keys_emb, values_emb, wtb, ixb, kb, vb);

    // 3b. v transpose: [B,H,S,D] -> [B,H,D,S]
    tr64<<<dim3(16, 16, BB * HH), 256, 0, stream>>>(vb, vt);

    // 4. q = (xb @ Wqb^T) * d^-0.5 -> qc [B,S,H*D] bf16   (vb slot now free)
    mgemm<bf16, 0><<<dim3(64, 16, 1), 256, 0, stream>>>(
        xb, Wqb, qc, 1024, 1024, 1024, 8192,
        0, 0, 0, 0, 0, 0, 1, 0.03125f);

    // 5. scores = q @ k^T per (b,h), causal tile-skip -> scb bf16
    mgemm<bf16, 1><<<dim3(8, 8, BB * HH), 256, 0, stream>>>(
        qc, kb, scb, 1024, 8192, 1024, 1024,
        SLAB, (long long)DD, (long long)HH * SD, SD,
        (long long)HH * SS * SS, (long long)SS * SS, HH, 1.0f);

    // 6. causal softmax (fp32 compute, bf16 store; writes full rows)
    softmax_causal_bf<<<dim3(BB * HH * SS), 256, 0, stream>>>(scb);

    // 7. ctx = att @ v  (B = vt, B^T form), K limited to row0+128; ctx -> qc slab
    mgemm<bf16, 2><<<dim3(8, 8, BB * HH), 256, 0, stream>>>(
        scb, vt, qc, 1024, 1024, 1024, 8192,
        (long long)HH * SS * SS, (long long)SS * SS,
        (long long)HH * SD, SD,
        SLAB, (long long)DD, HH, 1.0f);

    // 7b. bf16 Wo (scores dead now)
    cvt_bf<<<dim3(8192), 256, 0, stream>>>(Wo, Wob, 8388608LL);

    // 8. out = ctx @ Wo^T  (fp32 out)
    mgemm<float, 0><<<dim3(8, 16, 1), 256, 0, stream>>>(
        qc, Wob, out, 8192, 8192, 8192, 1024,
        0, 0, 0, 0, 0, 0, 1, 1.0f);
}

// Round 6
// 434.509 us; speedup vs baseline: 4.3057x; 1.1892x over previous
//
#include <hip/hip_runtime.h>
#include <hip/hip_bf16.h>

// Problem constants
#define BB   2
#define SS   1024
#define DD   1024
#define HH   8
#define NPP  2
#define NKK  32
#define DKK  64
#define TKK  8
#define NKV_ 1024

typedef __hip_bfloat16 bf16;
typedef __attribute__((ext_vector_type(8))) short bf16x8;
typedef __attribute__((ext_vector_type(4))) float f32x4;

using u32g = __attribute__((address_space(1))) unsigned int;
using u32l = __attribute__((address_space(3))) unsigned int;

// async global->LDS, 16B per lane; LDS dest = wave-uniform base + lane*16
#define GLDS16(g, l) __builtin_amdgcn_global_load_lds((const u32g*)(g), (u32l*)(l), 16, 0, 0)

// ---- scalar/vec conversion helpers ----
__device__ inline unsigned short f2b(float f) {       // RNE f32->bf16
    unsigned x = __float_as_uint(f);
    return (unsigned short)((x + 0x7fffu + ((x >> 16) & 1u)) >> 16);
}
__device__ inline float b2f(unsigned short u) {
    return __uint_as_float(((unsigned)u) << 16);
}

// fp32 -> bf16 convert, 4 elems/thread
__global__ __launch_bounds__(256) void cvt_bf(const float* __restrict__ src,
                                              bf16* __restrict__ dst, long long n)
{
    long long i = ((long long)blockIdx.x * 256 + threadIdx.x) * 4;
    if (i >= n) return;
    float4 v = *(const float4*)&src[i];
    ushort4 u; u.x = f2b(v.x); u.y = f2b(v.y); u.z = f2b(v.z); u.w = f2b(v.w);
    *(ushort4*)&dst[i] = u;
}

// split-K reduction: out[i] = scale * sum_s p[i + s*n], float4 per thread
__global__ __launch_bounds__(256) void reduce_split(
    const float* __restrict__ p, float* __restrict__ out,
    long long n, int nsplit, float scale)
{
    long long i = ((long long)blockIdx.x * 256 + threadIdx.x) * 4;
    if (i >= n) return;
    float4 a = *(const float4*)&p[i];
    for (int s = 1; s < nsplit; ++s) {
        float4 b = *(const float4*)&p[i + (long long)s * n];
        a.x += b.x; a.y += b.y; a.z += b.z; a.w += b.w;
    }
    a.x *= scale; a.y *= scale; a.z *= scale; a.w *= scale;
    *(float4*)&out[i] = a;
}

// ============================================================================
// MFMA bf16 GEMM (m97 structure + T2 XOR swizzle + T1 XCD swizzle):
//   C[m,n] = scale * sum_k A[m][k] * B[n][k]
// 128x128 tile, BK=64, 4 waves (2x2 of 64x64), mfma_f32_16x16x32_bf16.
// LDS(row, chunk) = global(row, chunk ^ (row&7)), 16B chunks (rule #21:
// pre-swizzled global source, linear LDS dest, same XOR on ds_read).
// CAUSAL==1: skip tiles above diagonal. CAUSAL==2: Klim = row0+128.
// Split-K is expressed via the z-slab strides (sAb/sBb = k-offset,
// sCb = partial-slab stride, zH=1). NOTE: gx*gy*gz % 8 == 0 required.
// ============================================================================
template<typename TC, int CAUSAL>
__global__ __launch_bounds__(256) void mgemm(
    const bf16* __restrict__ A, const bf16* __restrict__ B, TC* __restrict__ C,
    int K, int lda, int ldb, int ldc,
    long long sAb, long long sAh, long long sBb, long long sBh,
    long long sCb, long long sCh, int zH, float scale)
{
    // T1: chunked XCD swizzle over the full linear grid (bijective: nwg%8==0)
    int gx = gridDim.x, gy = gridDim.y;
    int nwg = gx * gy * gridDim.z;
    int hw  = (blockIdx.z * gy + blockIdx.y) * gx + blockIdx.x;
    int w   = (hw & 7) * (nwg >> 3) + (hw >> 3);
    int bx  = w % gx;
    int rem = w / gx;
    int by  = rem % gy;
    int z   = rem / gy;

    int zb = z / zH, zh = z % zH;
    A += (long long)zb * sAb + (long long)zh * sAh;
    B += (long long)zb * sBb + (long long)zh * sBh;
    C += (long long)zb * sCb + (long long)zh * sCh;

    int row0 = by * 128, col0 = bx * 128;
    if (CAUSAL == 1 && col0 > row0 + 127) return;
    int Klim = (CAUSAL == 2) ? min(K, row0 + 128) : K;

    __shared__ short sh[16384];          // As = [0:8192), Bs = [8192:16384)
    short* As = sh;
    short* Bs = sh + 8192;

    int tid = threadIdx.x, wave = tid >> 6, lane = tid & 63;
    int wr = wave >> 1, wc = wave & 1;       // wave's 64x64 quadrant
    int lr = lane & 15, lg = lane >> 4;      // frag row / k-group

    f32x4 zero = {0.f, 0.f, 0.f, 0.f};
    f32x4 acc[4][4];
    #pragma unroll
    for (int m = 0; m < 4; ++m)
        #pragma unroll
        for (int n = 0; n < 4; ++n) acc[m][n] = zero;

    // staging: wave stages 32 rows of A and B per K-step; one GLDS16 = 8 rows.
    int srow = wave * 32 + (lane >> 3);
    int scol = ((lane & 7) ^ (lane >> 3)) * 8;
    int fo = (lg ^ (lr & 7)) * 8;            // frag-read swizzle; kk=1 -> fo^32

    for (int k0 = 0; k0 < Klim; k0 += 64) {
        const bf16* Ak = A + (long long)(row0 + srow) * lda + k0 + scol;
        const bf16* Bk = B + (long long)(col0 + srow) * ldb + k0 + scol;
        #pragma unroll
        for (int i = 0; i < 4; ++i) {
            GLDS16(Ak + (long long)i * 8 * lda, &As[(wave * 32 + i * 8) * 64]);
            GLDS16(Bk + (long long)i * 8 * ldb, &Bs[(wave * 32 + i * 8) * 64]);
        }
        asm volatile("s_waitcnt vmcnt(0)" ::: "memory");
        __syncthreads();

        #pragma unroll
        for (int kk = 0; kk < 2; ++kk) {
            bf16x8 af[4], bfr[4];
            #pragma unroll
            for (int m = 0; m < 4; ++m)
                af[m] = *(const bf16x8*)&As[(wr * 64 + m * 16 + lr) * 64 + (fo ^ (kk * 32))];
            #pragma unroll
            for (int n = 0; n < 4; ++n)
                bfr[n] = *(const bf16x8*)&Bs[(wc * 64 + n * 16 + lr) * 64 + (fo ^ (kk * 32))];
            #pragma unroll
            for (int m = 0; m < 4; ++m)
                #pragma unroll
                for (int n = 0; n < 4; ++n)
                    acc[m][n] = __builtin_amdgcn_mfma_f32_16x16x32_bf16(
                        af[m], bfr[n], acc[m][n], 0, 0, 0);
        }
        __syncthreads();
    }

    // C/D layout: col = lane&15, row = (lane>>4)*4 + r  [m89-verified]
    if constexpr (sizeof(TC) == 2) {
        // bf16 out: stage quadrant in LDS (swizzled), then 16B coalesced stores
        short* cs = &sh[wave * 4096];        // 64x64 bf16 per-wave region
        #pragma unroll
        for (int m = 0; m < 4; ++m)
            #pragma unroll
            for (int n = 0; n < 4; ++n)
                #pragma unroll
                for (int r = 0; r < 4; ++r) {
                    int rl = m * 16 + lg * 4 + r;
                    int cc = (n * 2 + (lr >> 3)) ^ (rl & 7);
                    cs[rl * 64 + cc * 8 + (lr & 7)] =
                        (short)f2b(scale * acc[m][n][r]);
                }
        #pragma unroll
        for (int i = 0; i < 8; ++i) {
            int rl = i * 8 + (lane >> 3);
            int ch = (lane & 7) ^ (lane >> 3);
            bf16x8 v = *(const bf16x8*)&cs[rl * 64 + ch * 8];
            *(bf16x8*)&C[(long long)(row0 + wr * 64 + rl) * ldc
                         + col0 + wc * 64 + (lane & 7) * 8] = v;
        }
    } else {
        #pragma unroll
        for (int m = 0; m < 4; ++m) {
            int row = row0 + wr * 64 + m * 16 + lg * 4;
            #pragma unroll
            for (int n = 0; n < 4; ++n) {
                int col = col0 + wc * 64 + n * 16 + lr;
                #pragma unroll
                for (int r = 0; r < 4; ++r)
                    C[(long long)(row + r) * ldc + col] = scale * acc[m][n][r];
            }
        }
    }
}

// ============================================================================
// pq fixup: exact-fp32 recompute of pq rows for s < 64 (both batches).
// Routing index-selection is only output-sensitive at small s (causal
// attention concentrates there) — everywhere else bf16 pq is safe.
// ============================================================================
#define TILE 64
#define KT   16
#define LPAD 4
__global__ __launch_bounds__(256) void pq_fix(
    const float* __restrict__ A, const float* __restrict__ Bm, float* __restrict__ C)
{
    long long zo = (long long)blockIdx.z * 1024 * 1024;   // per-batch row offset
    A += zo; C += zo;
    int col0 = blockIdx.x * TILE;
    __shared__ float As[KT][TILE + LPAD];
    __shared__ float Bs[KT][TILE + LPAD];
    int tid = threadIdx.x, tx = tid % 16, ty = tid / 16;
    float acc[4][4] = {{0.f}};
    int lr = tid / 4, lk = (tid % 4) * 4;

    for (int k0 = 0; k0 < 1024; k0 += KT) {
        float4 va = *(const float4*)&A[(long long)lr * 1024 + k0 + lk];
        As[lk + 0][lr] = va.x; As[lk + 1][lr] = va.y;
        As[lk + 2][lr] = va.z; As[lk + 3][lr] = va.w;
        float4 vb = *(const float4*)&Bm[(long long)(col0 + lr) * 1024 + k0 + lk];
        Bs[lk + 0][lr] = vb.x; Bs[lk + 1][lr] = vb.y;
        Bs[lk + 2][lr] = vb.z; Bs[lk + 3][lr] = vb.w;
        __syncthreads();
        #pragma unroll
        for (int kk = 0; kk < KT; ++kk) {
            float a[4], b[4];
            #pragma unroll
            for (int i = 0; i < 4; ++i) a[i] = As[kk][ty * 4 + i];
            #pragma unroll
            for (int j = 0; j < 4; ++j) b[j] = Bs[kk][tx * 4 + j];
            #pragma unroll
            for (int i = 0; i < 4; ++i)
                #pragma unroll
                for (int j = 0; j < 4; ++j)
                    acc[i][j] = fmaf(a[i], b[j], acc[i][j]);
        }
        __syncthreads();
    }
    #pragma unroll
    for (int i = 0; i < 4; ++i)
        *(float4*)&C[(long long)(ty * 4 + i) * 1024 + col0 + tx * 4] =
            make_float4(acc[i][0], acc[i][1], acc[i][2], acc[i][3]);
}

// ============================================================================
// Product-key routing, wave-parallel (1 wave per (b,s,h), 4 waves/block).
// jax.lax.top_k semantics: descending, ties -> lowest index. fp32 scores.
// ============================================================================
__global__ __launch_bounds__(256) void pk_route(
    const float* __restrict__ pq, const float* __restrict__ pkk,
    float* __restrict__ wts, int* __restrict__ idxs)
{
    int bid  = blockIdx.x * 4 + (threadIdx.x >> 6);   // (b*S+s)*H + h
    int lane = threadIdx.x & 63;
    int h    = bid % HH;
    long long bs = bid / HH;
    int p = lane >> 5, n = lane & 31;

    const float* pv = pq  + (bs * NPP + p) * (HH * DKK) + h * DKK;
    const float* kv = pkk + ((long long)(p * NKK + n) * HH + h) * DKK;
    float s = 0.f;
    #pragma unroll
    for (int d = 0; d < DKK; d += 4) {
        float4 q4 = *(const float4*)&pv[d];
        float4 k4 = *(const float4*)&kv[d];
        s = fmaf(q4.x, k4.x, fmaf(q4.y, k4.y, fmaf(q4.z, k4.z, fmaf(q4.w, k4.w, s))));
    }

    // ---- stage 1: top-8 of 32 within each half (p=0: lanes 0-31, p=1: 32-63)
    float myv = s;
    float keepv = 0.f; int keepn = 0;     // lane r (n==r, r<8) holds rank-r
    #pragma unroll
    for (int r = 0; r < TKK; ++r) {
        float bv = myv; int bn = n;
        #pragma unroll
        for (int off = 1; off < 32; off <<= 1) {
            float ov = __shfl_xor(bv, off);
            int   on = __shfl_xor(bn, off);
            if (ov > bv || (ov == bv && on < bn)) { bv = ov; bn = on; }
        }
        if (n == r) { keepv = bv; keepn = bn; }
        if (n == bn) myv = -INFINITY;     // mask this half's winner
    }

    // ---- stage 2: combine; lane f = i*8+j holds psc0[i]+psc1[j]
    int ci = lane >> 3, cj = lane & 7;
    float c0 = __shfl(keepv, ci);         // half-0 rank-ci
    int   n0 = __shfl(keepn, ci);
    float c1 = __shfl(keepv, 32 + cj);    // half-1 rank-cj
    int   n1 = __shfl(keepn, 32 + cj);
    float cv = c0 + c1;
    int cidx = n0 + n1 * NKK;

    float myc = cv;
    float fsv = 0.f; int fsi = 0;         // lane r<8 holds final rank-r
    float m0 = 0.f;
    #pragma unroll
    for (int r = 0; r < TKK; ++r) {
        float bv = myc; int bf = lane;
        #pragma unroll
        for (int off = 1; off < 64; off <<= 1) {
            float ov = __shfl_xor(bv, off);
            int   of = __shfl_xor(bf, off);
            if (ov > bv || (ov == bv && of < bf)) { bv = ov; bf = of; }
        }
        if (r == 0) m0 = bv;
        int widx = __shfl(cidx, bf);
        if (lane == r) { fsv = bv; fsi = widx; }
        if (lane == bf) myc = -INFINITY;
    }

    // ---- softmax over the 8 winners (lanes 0..7)
    float e = (lane < TKK) ? expf(fsv - m0) : 0.f;
    float sum = e;
    #pragma unroll
    for (int off = 1; off < 8; off <<= 1) sum += __shfl_xor(sum, off);
    if (lane < TKK) {
        wts[(long long)bid * TKK + lane]  = e / sum;
        idxs[(long long)bid * TKK + lane] = fsi + h * NKV_;
    }
}

// Weighted 8-row embedding-bag gather -> k,v in [B,H,S,D], bf16 out.
__global__ __launch_bounds__(256) void gather_kv(
    const float* __restrict__ ke, const float* __restrict__ ve,
    const float* __restrict__ wts, const int* __restrict__ idxs,
    bf16* __restrict__ kb, bf16* __restrict__ vb)
{
    int bid = blockIdx.x;                 // (b*S+s)*H + h
    int h = bid % HH;
    int bs = bid / HH;
    int b = bs / SS, s = bs % SS;

    float w[TKK]; int rix[TKK];
    #pragma unroll
    for (int t = 0; t < TKK; ++t) {
        w[t]   = wts[(long long)bid * TKK + t];
        rix[t] = idxs[(long long)bid * TKK + t];
    }
    int c0 = threadIdx.x * 4;
    float4 ak = {0.f,0.f,0.f,0.f}, av = {0.f,0.f,0.f,0.f};
    #pragma unroll
    for (int t = 0; t < TKK; ++t) {
        float4 kr = *(const float4*)&ke[(long long)rix[t] * DD + c0];
        float4 vr = *(const float4*)&ve[(long long)rix[t] * DD + c0];
        ak.x += w[t]*kr.x; ak.y += w[t]*kr.y; ak.z += w[t]*kr.z; ak.w += w[t]*kr.w;
        av.x += w[t]*vr.x; av.y += w[t]*vr.y; av.z += w[t]*vr.z; av.w += w[t]*vr.w;
    }
    long long off = ((long long)(b * HH + h) * SS + s) * DD + c0;
    ushort4 uk; uk.x=f2b(ak.x); uk.y=f2b(ak.y); uk.z=f2b(ak.z); uk.w=f2b(ak.w);
    ushort4 uv; uv.x=f2b(av.x); uv.y=f2b(av.y); uv.z=f2b(av.z); uv.w=f2b(av.w);
    *(ushort4*)&kb[off] = uk;
    *(ushort4*)&vb[off] = uv;
}

// 64x64 LDS transpose: vb [z][S][D] -> vt [z][D][S], bf16.
__global__ __launch_bounds__(256) void tr64(const bf16* __restrict__ src,
                                            bf16* __restrict__ dst)
{
    __shared__ unsigned short t[64][65];
    long long z = blockIdx.z;
    const unsigned short* s = (const unsigned short*)src + z * SS * DD;
    unsigned short* d = (unsigned short*)dst + z * DD * SS;
    int s0 = blockIdx.x * 64;             // S-block
    int d0 = blockIdx.y * 64;             // D-block
    int tid = threadIdx.x;
    int r = tid / 16, c4 = (tid % 16) * 4;
    #pragma unroll
    for (int i = 0; i < 4; ++i) {
        int sr = r + i * 16;
        ushort4 v = *(const ushort4*)&s[(long long)(s0 + sr) * DD + d0 + c4];
        t[sr][c4] = v.x; t[sr][c4+1] = v.y; t[sr][c4+2] = v.z; t[sr][c4+3] = v.w;
    }
    __syncthreads();
    #pragma unroll
    for (int i = 0; i < 4; ++i) {
        int dr = r + i * 16;              // D index
        ushort4 v;
        v.x = t[c4][dr]; v.y = t[c4+1][dr]; v.z = t[c4+2][dr]; v.w = t[c4+3][dr];
        *(ushort4*)&d[(long long)(d0 + dr) * SS + s0 + c4] = v;
    }
}

// Causal softmax on bf16 score rows; fp32 compute, writes entire row.
__global__ __launch_bounds__(256) void softmax_causal_bf(bf16* __restrict__ sc)
{
    int r  = blockIdx.x;                  // (b*H+h)*S + sq
    int sq = r % SS;
    unsigned short* row = (unsigned short*)(sc + (long long)r * SS);
    int t = threadIdx.x;
    int nvalid = sq + 1;

    float v[4];
    float lm = -INFINITY;
    #pragma unroll
    for (int i = 0; i < 4; ++i) {
        int j = t + i * 256;
        v[i] = (j < nvalid) ? b2f(row[j]) : -INFINITY;
        lm = fmaxf(lm, v[i]);
    }
    __shared__ float red[256];
    red[t] = lm; __syncthreads();
    for (int o = 128; o > 0; o >>= 1) {
        if (t < o) red[t] = fmaxf(red[t], red[t + o]);
        __syncthreads();
    }
    float m = red[0];
    __syncthreads();

    float e[4], ls = 0.f;
    #pragma unroll
    for (int i = 0; i < 4; ++i) {
        int j = t + i * 256;
        e[i] = (j < nvalid) ? expf(v[i] - m) : 0.f;
        ls += e[i];
    }
    red[t] = ls; __syncthreads();
    for (int o = 128; o > 0; o >>= 1) {
        if (t < o) red[t] += red[t + o];
        __syncthreads();
    }
    float inv = 1.f / red[0];
    #pragma unroll
    for (int i = 0; i < 4; ++i) row[t + i * 256] = f2b(e[i] * inv);
}

extern "C" void kernel_launch(void* const* d_in, const int* in_sizes, int n_in,
                              void* d_out, int out_size, void* d_ws, size_t ws_size,
                              hipStream_t stream)
{
    const float* inputs     = (const float*)d_in[0];
    const float* Wq         = (const float*)d_in[1];
    const float* Wpk        = (const float*)d_in[2];
    const float* pk_keys    = (const float*)d_in[3];
    const float* keys_emb   = (const float*)d_in[4];
    const float* values_emb = (const float*)d_in[5];
    const float* Wo         = (const float*)d_in[6];
    float* out = (float*)d_out;

    // ---- workspace layout (129 MB, aliased) ----
    const long long MB = 1LL << 20;
    char* base = (char*)d_ws;
    bf16* kb  = (bf16*)(base);            // [B,H,S,D]  32MB  (also split-K partials)
    float* spl = (float*)base;            // split-K partials (steps 1,8): up to 32MB
    bf16* vb  = (bf16*)(base + 32*MB);    // [B,H,S,D]  32MB; later q / ctx slab
    bf16* vt  = (bf16*)(base + 64*MB);    // [B,H,D,S]  32MB
    char* screg = base + 96*MB;           // 32MB multi-use region
    bf16* scb = (bf16*)screg;             // scores [B*H,S,S] (steps 5-7)
    float* pqb = (float*)screg;           // [0:8MB)   pq fp32 (steps 1-2)
    bf16* Wpkb = (bf16*)(screg + 8*MB);   // [8:10MB)  bf16 Wpk (step 1)
    bf16* Wqb  = (bf16*)(screg + 10*MB);  // [10:26MB) bf16 Wq (step 4)
    bf16* xb   = (bf16*)(screg + 26*MB);  // [26:30MB) bf16 inputs (steps 1,4)
    bf16* Wob  = (bf16*)screg;            // [0:16MB)  bf16 Wo (after step 7)
    float* wtb = (float*)(base + 128*MB); // routing weights fp32
    int*   ixb = (int*)(base + 128*MB + (512<<10));
    size_t needed = (size_t)(129*MB);
    if (ws_size < needed) return;

    bf16* qc  = vb;                       // q then ctx, [B,S,H*D] (vb dead after tr64)
    const long long SLAB = (long long)SS * HH * DD;     // 8,388,608
    const long long SD   = (long long)SS * DD;          // 1,048,576
    const long long OUTN = 2048LL * 1024;               // 2,097,152

    // 0. bf16 copies of inputs, Wpk, Wq (into score region; dead before step 5)
    cvt_bf<<<dim3(2048), 256, 0, stream>>>(inputs, xb, 2097152LL);
    cvt_bf<<<dim3(1024), 256, 0, stream>>>(Wpk, Wpkb, 1048576LL);
    cvt_bf<<<dim3(8192), 256, 0, stream>>>(Wq, Wqb, 8388608LL);

    // 1. pq = xb @ Wpkb^T via MFMA, split-K=2 (K=512 each) -> partials in spl
    mgemm<float, 0><<<dim3(8, 16, 2), 256, 0, stream>>>(
        xb, Wpkb, spl, 512, 1024, 1024, 1024,
        512, 0, 512, 0, OUTN, 0, 1, 1.0f);
    reduce_split<<<dim3(2048), 256, 0, stream>>>(spl, pqb, OUTN, 2, 1.0f);

    // 1b. exact-fp32 fixup of rows s<64 (both batches)
    pq_fix<<<dim3(16, 1, 2), 256, 0, stream>>>(inputs, Wpk, pqb);

    // 2. product-key routing -> fp32 weights + row indices (wave-parallel)
    pk_route<<<dim3(BB * SS * HH / 4), 256, 0, stream>>>(pqb, pk_keys, wtb, ixb);

    // 3. weighted embedding gather -> k,v [B,H,S,D] bf16 (kb overwrites spl)
    gather_kv<<<dim3(BB * SS * HH), 256, 0, stream>>>(
        keys_emb, values_emb, wtb, ixb, kb, vb);

    // 3b. v transpose: [B,H,S,D] -> [B,H,D,S]
    tr64<<<dim3(16, 16, BB * HH), 256, 0, stream>>>(vb, vt);

    // 4. q = (xb @ Wqb^T) * d^-0.5 -> qc [B,S,H*D] bf16   (vb slot now free)
    mgemm<bf16, 0><<<dim3(64, 16, 1), 256, 0, stream>>>(
        xb, Wqb, qc, 1024, 1024, 1024, 8192,
        0, 0, 0, 0, 0, 0, 1, 0.03125f);

    // 5. scores = q @ k^T per (b,h), causal tile-skip -> scb bf16
    mgemm<bf16, 1><<<dim3(8, 8, BB * HH), 256, 0, stream>>>(
        qc, kb, scb, 1024, 8192, 1024, 1024,
        SLAB, (long long)DD, (long long)HH * SD, SD,
        (long long)HH * SS * SS, (long long)SS * SS, HH, 1.0f);

    // 6. causal softmax (fp32 compute, bf16 store; writes full rows)
    softmax_causal_bf<<<dim3(BB * HH * SS), 256, 0, stream>>>(scb);

    // 7. ctx = att @ v  (B = vt, B^T form), K limited to row0+128; ctx -> qc slab
    //    (kb dead after step 5 -> spl region reusable for step 8 partials)
    mgemm<bf16, 2><<<dim3(8, 8, BB * HH), 256, 0, stream>>>(
        scb, vt, qc, 1024, 1024, 1024, 8192,
        (long long)HH * SS * SS, (long long)SS * SS,
        (long long)HH * SD, SD,
        SLAB, (long long)DD, HH, 1.0f);

    // 7b. bf16 Wo (scores dead now)
    cvt_bf<<<dim3(8192), 256, 0, stream>>>(Wo, Wob, 8388608LL);

    // 8. out = ctx @ Wo^T, split-K=4 (K=2048 each) -> partials in spl, reduce
    mgemm<float, 0><<<dim3(8, 16, 4), 256, 0, stream>>>(
        qc, Wob, spl, 2048, 8192, 8192, 1024,
        2048, 0, 2048, 0, OUTN, 0, 1, 1.0f);
    reduce_split<<<dim3(2048), 256, 0, stream>>>(spl, out, OUTN, 4, 1.0f);
}